// Round 1
// baseline (810.975 us; speedup 1.0000x reference)
//
#include <hip/hip_runtime.h>

typedef unsigned short u16;
typedef unsigned int u32;
typedef __attribute__((ext_vector_type(4))) float f32x4;
typedef __attribute__((ext_vector_type(8))) short bf16x8;   // 8 bf16 (4 VGPRs)
typedef __attribute__((ext_vector_type(4))) u16 u16x4;

#define DEV __device__ __forceinline__

DEV u16 f2bf(float f) {               // RNE fp32 -> bf16
  union { float f; u32 u; } c; c.f = f;
  u32 u = c.u;
  u += 0x7fffu + ((u >> 16) & 1u);
  return (u16)(u >> 16);
}
DEV float bf2f(u16 h) {
  union { u32 u; float f; } c; c.u = ((u32)h) << 16;
  return c.f;
}

// ---------------- elementwise fp32 -> bf16 hi/lo split ----------------
__global__ __launch_bounds__(256) void convert_split(const float* __restrict__ in,
                                                     u16* __restrict__ hi,
                                                     u16* __restrict__ lo) {
  int i = (blockIdx.x * 256 + threadIdx.x) * 4;
  f32x4 v = *(const f32x4*)(in + i);
  u16x4 h, l;
#pragma unroll
  for (int j = 0; j < 4; ++j) {
    h[j] = f2bf(v[j]);
    l[j] = f2bf(v[j] - bf2f(h[j]));
  }
  *(u16x4*)(hi + i) = h;
  *(u16x4*)(lo + i) = l;
}

// ---------------- mask (S,S) int32 -> bitmask (1 bit per entry) ----------------
__global__ __launch_bounds__(256) void pack_mask(const int* __restrict__ m,
                                                 unsigned long long* __restrict__ out) {
  size_t i = (size_t)blockIdx.x * 256 + threadIdx.x;
  unsigned long long b = __ballot(m[i] != 0);
  if ((threadIdx.x & 63) == 0) out[i >> 6] = b;
}

// ---------------- fp32 weight (R,C) -> transposed bf16 hi/lo (C,R) ----------------
__global__ void wtrans(const float* __restrict__ W, u16* __restrict__ Th,
                       u16* __restrict__ Tl, int R, int C) {
  __shared__ float t[32][33];
  int c0 = blockIdx.x * 32, r0 = blockIdx.y * 32;
  int tx = threadIdx.x, ty = threadIdx.y;  // (32,8)
#pragma unroll
  for (int i = 0; i < 4; ++i)
    t[ty + 8 * i][tx] = W[(size_t)(r0 + ty + 8 * i) * C + c0 + tx];
  __syncthreads();
#pragma unroll
  for (int i = 0; i < 4; ++i) {
    float v = t[tx][ty + 8 * i];
    u16 h = f2bf(v);
    size_t o = (size_t)(c0 + ty + 8 * i) * R + r0 + tx;
    Th[o] = h;
    Tl[o] = f2bf(v - bf2f(h));
  }
}

// ---------------- u16 transpose (R,C) -> (C,R) ----------------
__global__ void transpose_u16(const u16* __restrict__ in, u16* __restrict__ out,
                              int R, int C) {
  __shared__ u16 t[32][33];
  int c0 = blockIdx.x * 32, r0 = blockIdx.y * 32;
  int tx = threadIdx.x, ty = threadIdx.y;  // (32,8)
#pragma unroll
  for (int i = 0; i < 4; ++i)
    t[ty + 8 * i][tx] = in[(size_t)(r0 + ty + 8 * i) * C + c0 + tx];
  __syncthreads();
#pragma unroll
  for (int i = 0; i < 4; ++i)
    out[(size_t)(c0 + ty + 8 * i) * R + r0 + tx] = t[tx][ty + 8 * i];
}

// ---------------- GEMM: C[M,N] = A[M,K] @ B^T[N,K] + bias ----------------
// A, B given as bf16 (optionally hi+lo split for ~fp32 accuracy: 3 MFMAs).
// 128x128 block tile, 4 waves each 64x64 (4x4 grid of 16x16x32 MFMA).
// Fragments loaded straight from global (L1/L2-served); no LDS in round 0.
struct GemmIO {
  const u16* Bh; const u16* Bl; const float* bias;
  float* Cf; u16* Ch; u16* Cl;
};

template <int SPLIT, int RELU>
__global__ __launch_bounds__(256) void gemm_bt(const u16* __restrict__ Ah,
                                               const u16* __restrict__ Al,
                                               GemmIO io0, GemmIO io1, GemmIO io2,
                                               int M, int N, int K) {
  int z = blockIdx.z;
  GemmIO io = (z == 0) ? io0 : (z == 1 ? io1 : io2);
  const int bn = blockIdx.x * 128, bm = blockIdx.y * 128;
  const int tid = threadIdx.x;
  const int wave = tid >> 6, lane = tid & 63;
  const int l16 = lane & 15, quad = lane >> 4;
  const int wm = (wave >> 1) * 64, wn = (wave & 1) * 64;
  const int arow = bm + wm + l16;
  const int brow = bn + wn + l16;

  f32x4 acc[4][4] = {};

  for (int kt = 0; kt < K; kt += 32) {
    const int koff = kt + quad * 8;
    bf16x8 a_h[4], b_h[4], a_l[4], b_l[4];
#pragma unroll
    for (int mt = 0; mt < 4; ++mt)
      a_h[mt] = *(const bf16x8*)(Ah + (size_t)(arow + mt * 16) * K + koff);
#pragma unroll
    for (int nt = 0; nt < 4; ++nt)
      b_h[nt] = *(const bf16x8*)(io.Bh + (size_t)(brow + nt * 16) * K + koff);
    if (SPLIT) {
#pragma unroll
      for (int mt = 0; mt < 4; ++mt)
        a_l[mt] = *(const bf16x8*)(Al + (size_t)(arow + mt * 16) * K + koff);
#pragma unroll
      for (int nt = 0; nt < 4; ++nt)
        b_l[nt] = *(const bf16x8*)(io.Bl + (size_t)(brow + nt * 16) * K + koff);
    }
#pragma unroll
    for (int mt = 0; mt < 4; ++mt)
#pragma unroll
      for (int nt = 0; nt < 4; ++nt) {
        acc[mt][nt] = __builtin_amdgcn_mfma_f32_16x16x32_bf16(a_h[mt], b_h[nt], acc[mt][nt], 0, 0, 0);
        if (SPLIT) {
          acc[mt][nt] = __builtin_amdgcn_mfma_f32_16x16x32_bf16(a_h[mt], b_l[nt], acc[mt][nt], 0, 0, 0);
          acc[mt][nt] = __builtin_amdgcn_mfma_f32_16x16x32_bf16(a_l[mt], b_h[nt], acc[mt][nt], 0, 0, 0);
        }
      }
  }

  // Epilogue. C/D layout: col = lane&15, row = quad*4 + reg  [m89-verified]
#pragma unroll
  for (int mt = 0; mt < 4; ++mt)
#pragma unroll
    for (int nt = 0; nt < 4; ++nt) {
      int col = bn + wn + nt * 16 + l16;
      float bv = io.bias ? io.bias[col] : 0.f;
#pragma unroll
      for (int r = 0; r < 4; ++r) {
        int row = bm + wm + mt * 16 + quad * 4 + r;
        float v = acc[mt][nt][r] + bv;
        if (RELU) v = fmaxf(v, 0.f);
        size_t oidx = (size_t)row * N + col;
        if (io.Cf) io.Cf[oidx] = v;
        if (io.Ch) {
          u16 h = f2bf(v);
          io.Ch[oidx] = h;
          if (io.Cl) io.Cl[oidx] = f2bf(v - bf2f(h));
        }
      }
    }
}

// ---------------- flash attention ----------------
// Grid (64, 8): 64 q-blocks of 64 rows, 8 heads. 4 waves/block, 16 q-rows/wave.
// Q,K bf16 hi/lo split (accurate logits); V single bf16 pre-transposed (Dh-major).
// Online softmax; P goes C-layout -> LDS -> A-layout (m120 pattern).
__global__ __launch_bounds__(256) void attn(const u16* __restrict__ Qh, const u16* __restrict__ Ql,
                                            const u16* __restrict__ Kh, const u16* __restrict__ Kl,
                                            const u16* __restrict__ Vt, const u32* __restrict__ mb,
                                            u16* __restrict__ ctx) {
  const int S = 4096, D = 512;
  const float L2E = 1.44269504088896340736f;
  const int h = blockIdx.y;
  const int tid = threadIdx.x, wave = tid >> 6, lane = tid & 63;
  const int l16 = lane & 15, quad = lane >> 4;
  const int q0 = blockIdx.x * 64 + wave * 16;

  __shared__ u16 Pl[4][16 * 32];
  u16* myP = &Pl[wave][0];

  bf16x8 qh[2], ql[2];
  {
    size_t qb = (size_t)(q0 + l16) * D + h * 64 + quad * 8;
    qh[0] = *(const bf16x8*)(Qh + qb); qh[1] = *(const bf16x8*)(Qh + qb + 32);
    ql[0] = *(const bf16x8*)(Ql + qb); ql[1] = *(const bf16x8*)(Ql + qb + 32);
  }

  float m_run[4], l_run[4];
  f32x4 accO[4] = {};
#pragma unroll
  for (int r = 0; r < 4; ++r) { m_run[r] = -1e9f; l_run[r] = 0.f; }

  for (int kt = 0; kt < S; kt += 32) {
    f32x4 sc[2] = {};
#pragma unroll
    for (int st = 0; st < 2; ++st) {
      size_t kb = (size_t)(kt + st * 16 + l16) * D + h * 64 + quad * 8;
      bf16x8 kh0 = *(const bf16x8*)(Kh + kb), kh1 = *(const bf16x8*)(Kh + kb + 32);
      bf16x8 kl0 = *(const bf16x8*)(Kl + kb), kl1 = *(const bf16x8*)(Kl + kb + 32);
      sc[st] = __builtin_amdgcn_mfma_f32_16x16x32_bf16(qh[0], kh0, sc[st], 0, 0, 0);
      sc[st] = __builtin_amdgcn_mfma_f32_16x16x32_bf16(qh[1], kh1, sc[st], 0, 0, 0);
      sc[st] = __builtin_amdgcn_mfma_f32_16x16x32_bf16(qh[0], kl0, sc[st], 0, 0, 0);
      sc[st] = __builtin_amdgcn_mfma_f32_16x16x32_bf16(qh[1], kl1, sc[st], 0, 0, 0);
      sc[st] = __builtin_amdgcn_mfma_f32_16x16x32_bf16(ql[0], kh0, sc[st], 0, 0, 0);
      sc[st] = __builtin_amdgcn_mfma_f32_16x16x32_bf16(ql[1], kh1, sc[st], 0, 0, 0);
    }
    // mask: bit (k&31) of word mb[q*128 + k/32]; masked -> -1e9 (matches ref)
    u32 words[4];
#pragma unroll
    for (int r = 0; r < 4; ++r)
      words[r] = mb[(size_t)(q0 + quad * 4 + r) * 128 + (kt >> 5)];
#pragma unroll
    for (int st = 0; st < 2; ++st)
#pragma unroll
      for (int r = 0; r < 4; ++r)
        if (!((words[r] >> (st * 16 + l16)) & 1u)) sc[st][r] = -1e9f;

    float alpha[4];
#pragma unroll
    for (int r = 0; r < 4; ++r) {
      float t = fmaxf(sc[0][r], sc[1][r]);
      t = fmaxf(t, __shfl_xor(t, 1));
      t = fmaxf(t, __shfl_xor(t, 2));
      t = fmaxf(t, __shfl_xor(t, 4));
      t = fmaxf(t, __shfl_xor(t, 8));
      float mn = fmaxf(m_run[r], t);
      float al = exp2f((m_run[r] - mn) * L2E);
      m_run[r] = mn;
      float p0 = exp2f((sc[0][r] - mn) * L2E);
      float p1 = exp2f((sc[1][r] - mn) * L2E);
      sc[0][r] = p0; sc[1][r] = p1;
      float sum = p0 + p1;
      sum += __shfl_xor(sum, 1);
      sum += __shfl_xor(sum, 2);
      sum += __shfl_xor(sum, 4);
      sum += __shfl_xor(sum, 8);
      l_run[r] = l_run[r] * al + sum;
      alpha[r] = al;
    }
#pragma unroll
    for (int nt = 0; nt < 4; ++nt)
#pragma unroll
      for (int r = 0; r < 4; ++r) accO[nt][r] *= alpha[r];

    // P: C-layout -> LDS (wave-private)
#pragma unroll
    for (int st = 0; st < 2; ++st)
#pragma unroll
      for (int r = 0; r < 4; ++r)
        myP[(quad * 4 + r) * 32 + st * 16 + l16] = f2bf(sc[st][r]);
    __syncthreads();  // uniform trip count; orders LDS write->read conservatively

    bf16x8 pf = *(const bf16x8*)(myP + l16 * 32 + quad * 8);  // A-layout read
#pragma unroll
    for (int nt = 0; nt < 4; ++nt) {
      bf16x8 vf = *(const bf16x8*)(Vt + (size_t)(h * 64 + nt * 16 + l16) * S + kt + quad * 8);
      accO[nt] = __builtin_amdgcn_mfma_f32_16x16x32_bf16(pf, vf, accO[nt], 0, 0, 0);
    }
    __syncthreads();
  }

#pragma unroll
  for (int nt = 0; nt < 4; ++nt)
#pragma unroll
    for (int r = 0; r < 4; ++r) {
      float v = accO[nt][r] / l_run[r];
      ctx[(size_t)(q0 + quad * 4 + r) * D + h * 64 + nt * 16 + l16] = f2bf(v);
    }
}

// ---------------- residual + layernorm (rows of 512) ----------------
// 1 wave per row, 4 rows per block.
__global__ __launch_bounds__(256) void resid_ln(const float* __restrict__ X,
                                                const float* __restrict__ Y,
                                                const float* __restrict__ g,
                                                const float* __restrict__ b,
                                                float* __restrict__ outF,
                                                u16* __restrict__ outH) {
  int row = blockIdx.x * 4 + (int)(threadIdx.x >> 6);
  int lane = threadIdx.x & 63;
  const float* x0 = X + (size_t)row * 512;
  const float* y0 = Y + (size_t)row * 512;
  int c0 = lane * 4, c1 = 256 + lane * 4;
  f32x4 v0 = *(const f32x4*)(x0 + c0) + *(const f32x4*)(y0 + c0);
  f32x4 v1 = *(const f32x4*)(x0 + c1) + *(const f32x4*)(y0 + c1);
  float s = 0.f, s2 = 0.f;
#pragma unroll
  for (int j = 0; j < 4; ++j) {
    s += v0[j] + v1[j];
    s2 += v0[j] * v0[j] + v1[j] * v1[j];
  }
#pragma unroll
  for (int m = 1; m < 64; m <<= 1) {
    s += __shfl_xor(s, m);
    s2 += __shfl_xor(s2, m);
  }
  float mean = s * (1.f / 512.f);
  float var = s2 * (1.f / 512.f) - mean * mean;
  float rs = rsqrtf(var + 1e-5f);
  f32x4 o0, o1;
#pragma unroll
  for (int j = 0; j < 4; ++j) {
    o0[j] = (v0[j] - mean) * rs * g[c0 + j] + b[c0 + j];
    o1[j] = (v1[j] - mean) * rs * g[c1 + j] + b[c1 + j];
  }
  if (outF) {
    *(f32x4*)(outF + (size_t)row * 512 + c0) = o0;
    *(f32x4*)(outF + (size_t)row * 512 + c1) = o1;
  }
  if (outH) {
    u16x4 h0, h1;
#pragma unroll
    for (int j = 0; j < 4; ++j) { h0[j] = f2bf(o0[j]); h1[j] = f2bf(o1[j]); }
    *(u16x4*)(outH + (size_t)row * 512 + c0) = h0;
    *(u16x4*)(outH + (size_t)row * 512 + c1) = h1;
  }
}

extern "C" void kernel_launch(void* const* d_in, const int* in_sizes, int n_in,
                              void* d_out, int out_size, void* d_ws, size_t ws_size,
                              hipStream_t stream) {
  (void)in_sizes; (void)n_in; (void)out_size; (void)ws_size;
  const float* x   = (const float*)d_in[0];
  const int*   mask= (const int*)d_in[1];
  const float* wq  = (const float*)d_in[2];
  const float* bq  = (const float*)d_in[3];
  const float* wk  = (const float*)d_in[4];
  const float* bk  = (const float*)d_in[5];
  const float* wv  = (const float*)d_in[6];
  const float* bv  = (const float*)d_in[7];
  const float* wo  = (const float*)d_in[8];
  const float* bo  = (const float*)d_in[9];
  const float* w1  = (const float*)d_in[10];
  const float* b1  = (const float*)d_in[11];
  const float* w2  = (const float*)d_in[12];
  const float* b2  = (const float*)d_in[13];
  const float* g1  = (const float*)d_in[14];
  const float* be1 = (const float*)d_in[15];
  const float* g2  = (const float*)d_in[16];
  const float* be2 = (const float*)d_in[17];

  const int S = 4096, D = 512, F = 2048;
  char* ws = (char*)d_ws;
  size_t cur = 0;
  auto alloc = [&](size_t bytes) {
    char* p = ws + cur;
    cur += (bytes + 255) & ~(size_t)255;
    return p;
  };
  // persistent weight region (bf16, transposed to N x K)
  u16* wqT_h = (u16*)alloc((size_t)D * D * 2); u16* wqT_l = (u16*)alloc((size_t)D * D * 2);
  u16* wkT_h = (u16*)alloc((size_t)D * D * 2); u16* wkT_l = (u16*)alloc((size_t)D * D * 2);
  u16* wvT_h = (u16*)alloc((size_t)D * D * 2); u16* wvT_l = (u16*)alloc((size_t)D * D * 2);
  u16* woT_h = (u16*)alloc((size_t)D * D * 2); u16* woT_l = (u16*)alloc((size_t)D * D * 2);
  u16* w1T_h = (u16*)alloc((size_t)D * F * 2); u16* w1T_l = (u16*)alloc((size_t)D * F * 2);
  u16* w2T_h = (u16*)alloc((size_t)D * F * 2); u16* w2T_l = (u16*)alloc((size_t)D * F * 2);
  u32* mbits = (u32*)alloc((size_t)S * S / 8);
  u16* xh = (u16*)alloc((size_t)S * D * 2);
  u16* xl = (u16*)alloc((size_t)S * D * 2);
  u16* Qh = (u16*)alloc((size_t)S * D * 2);
  u16* Ql = (u16*)alloc((size_t)S * D * 2);
  u16* Kh = (u16*)alloc((size_t)S * D * 2);
  u16* Kl = (u16*)alloc((size_t)S * D * 2);
  u16* Vh = (u16*)alloc((size_t)S * D * 2);
  u16* Vt = (u16*)alloc((size_t)S * D * 2);
  u16* ctx = (u16*)alloc((size_t)S * D * 2);
  float* x1 = (float*)alloc((size_t)S * D * 4);
  u16* x1h = (u16*)alloc((size_t)S * D * 2);
  // aliased regions (lifetimes disjoint by stream order):
  float* proj = (float*)xh;   // 8 MB over xh+xl; written after QKV gemm consumed x
  u16* hbuf = Qh;             // 16 MB over Qh..Kl; written after attention
  float* ff2 = (float*)Vh;    // 8 MB over Vh+Vt; written after attention

  GemmIO ioQ = {wqT_h, wqT_l, bq, nullptr, Qh, Ql};
  GemmIO ioK = {wkT_h, wkT_l, bk, nullptr, Kh, Kl};
  GemmIO ioV = {wvT_h, wvT_l, bv, nullptr, Vh, nullptr};
  GemmIO ioP = {woT_h, nullptr, bo, proj, nullptr, nullptr};
  GemmIO io1 = {w1T_h, nullptr, b1, nullptr, hbuf, nullptr};
  GemmIO io2 = {w2T_h, nullptr, b2, ff2, nullptr, nullptr};

  dim3 tb(32, 8);
  // 1. converts
  convert_split<<<(S * D) / 1024, 256, 0, stream>>>(x, xh, xl);
  pack_mask<<<(S * S) / 256, 256, 0, stream>>>(mask, (unsigned long long*)mbits);
  wtrans<<<dim3(16, 16), tb, 0, stream>>>(wq, wqT_h, wqT_l, D, D);
  wtrans<<<dim3(16, 16), tb, 0, stream>>>(wk, wkT_h, wkT_l, D, D);
  wtrans<<<dim3(16, 16), tb, 0, stream>>>(wv, wvT_h, wvT_l, D, D);
  wtrans<<<dim3(16, 16), tb, 0, stream>>>(wo, woT_h, woT_l, D, D);
  wtrans<<<dim3(64, 16), tb, 0, stream>>>(w1, w1T_h, w1T_l, D, F);
  wtrans<<<dim3(16, 64), tb, 0, stream>>>(w2, w2T_h, w2T_l, F, D);
  // 2. QKV projections (split for accurate logits downstream)
  gemm_bt<1, 0><<<dim3(4, 32, 3), 256, 0, stream>>>(xh, xl, ioQ, ioK, ioV, S, D, D);
  // 3. V -> V^T (Dh-major) for PV B-fragments
  transpose_u16<<<dim3(16, 128), tb, 0, stream>>>(Vh, Vt, S, D);
  // 4. flash attention
  attn<<<dim3(64, 8), 256, 0, stream>>>(Qh, Ql, Kh, Kl, Vt, mbits, ctx);
  // 5. output projection
  gemm_bt<0, 0><<<dim3(4, 32, 1), 256, 0, stream>>>(ctx, nullptr, ioP, ioP, ioP, S, D, D);
  // 6. residual + LN1
  resid_ln<<<S / 4, 256, 0, stream>>>(x, proj, g1, be1, x1, x1h);
  // 7. FFN
  gemm_bt<0, 1><<<dim3(16, 32, 1), 256, 0, stream>>>(x1h, nullptr, io1, io1, io1, S, F, D);
  gemm_bt<0, 0><<<dim3(4, 32, 1), 256, 0, stream>>>(hbuf, nullptr, io2, io2, io2, S, D, F);
  // 8. residual + LN2 -> final fp32 output
  resid_ln<<<S / 4, 256, 0, stream>>>(x1, ff2, g2, be2, (float*)d_out, nullptr);
}

// Round 2
// 723.875 us; speedup vs baseline: 1.1203x; 1.1203x over previous
//
#include <hip/hip_runtime.h>

typedef unsigned short u16;
typedef unsigned int u32;
typedef __attribute__((ext_vector_type(4))) float f32x4;
typedef __attribute__((ext_vector_type(8))) short bf16x8;   // 8 bf16 (4 VGPRs)
typedef __attribute__((ext_vector_type(4))) u16 u16x4;

#define DEV __device__ __forceinline__

DEV u16 f2bf(float f) {               // RNE fp32 -> bf16
  union { float f; u32 u; } c; c.f = f;
  u32 u = c.u;
  u += 0x7fffu + ((u >> 16) & 1u);
  return (u16)(u >> 16);
}
DEV float bf2f(u16 h) {
  union { u32 u; float f; } c; c.u = ((u32)h) << 16;
  return c.f;
}
DEV u16 f2bf_trunc(float f) {         // truncating pack (p>=0; softmax normalizes the bias)
  union { float f; u32 u; } c; c.f = f;
  return (u16)(c.u >> 16);
}

// ---------------- elementwise fp32 -> bf16 hi/lo split ----------------
__global__ __launch_bounds__(256) void convert_split(const float* __restrict__ in,
                                                     u16* __restrict__ hi,
                                                     u16* __restrict__ lo) {
  int i = (blockIdx.x * 256 + threadIdx.x) * 4;
  f32x4 v = *(const f32x4*)(in + i);
  u16x4 h, l;
#pragma unroll
  for (int j = 0; j < 4; ++j) {
    h[j] = f2bf(v[j]);
    l[j] = f2bf(v[j] - bf2f(h[j]));
  }
  *(u16x4*)(hi + i) = h;
  *(u16x4*)(lo + i) = l;
}

// ---------------- mask (S,S) int32 -> bitmask (1 bit per entry) ----------------
__global__ __launch_bounds__(256) void pack_mask(const int* __restrict__ m,
                                                 unsigned long long* __restrict__ out) {
  size_t i = (size_t)blockIdx.x * 256 + threadIdx.x;
  unsigned long long b = __ballot(m[i] != 0);
  if ((threadIdx.x & 63) == 0) out[i >> 6] = b;
}

// ---------------- fp32 weight (R,C) -> transposed bf16 hi/lo (C,R) ----------------
__global__ void wtrans(const float* __restrict__ W, u16* __restrict__ Th,
                       u16* __restrict__ Tl, int R, int C) {
  __shared__ float t[32][33];
  int c0 = blockIdx.x * 32, r0 = blockIdx.y * 32;
  int tx = threadIdx.x, ty = threadIdx.y;  // (32,8)
#pragma unroll
  for (int i = 0; i < 4; ++i)
    t[ty + 8 * i][tx] = W[(size_t)(r0 + ty + 8 * i) * C + c0 + tx];
  __syncthreads();
#pragma unroll
  for (int i = 0; i < 4; ++i) {
    float v = t[tx][ty + 8 * i];
    u16 h = f2bf(v);
    size_t o = (size_t)(c0 + ty + 8 * i) * R + r0 + tx;
    Th[o] = h;
    Tl[o] = f2bf(v - bf2f(h));
  }
}

// ---------------- u16 transpose (R,C) -> (C,R) ----------------
__global__ void transpose_u16(const u16* __restrict__ in, u16* __restrict__ out,
                              int R, int C) {
  __shared__ u16 t[32][33];
  int c0 = blockIdx.x * 32, r0 = blockIdx.y * 32;
  int tx = threadIdx.x, ty = threadIdx.y;  // (32,8)
#pragma unroll
  for (int i = 0; i < 4; ++i)
    t[ty + 8 * i][tx] = in[(size_t)(r0 + ty + 8 * i) * C + c0 + tx];
  __syncthreads();
#pragma unroll
  for (int i = 0; i < 4; ++i)
    out[(size_t)(c0 + ty + 8 * i) * R + r0 + tx] = t[tx][ty + 8 * i];
}

// ---------------- GEMM: C[M,N] = A[M,K] @ B^T[N,K] + bias ----------------
struct GemmIO {
  const u16* Bh; const u16* Bl; const float* bias;
  float* Cf; u16* Ch; u16* Cl;
};

template <int SPLIT, int RELU>
__global__ __launch_bounds__(256) void gemm_bt(const u16* __restrict__ Ah,
                                               const u16* __restrict__ Al,
                                               GemmIO io0, GemmIO io1, GemmIO io2,
                                               int M, int N, int K) {
  int z = blockIdx.z;
  GemmIO io = (z == 0) ? io0 : (z == 1 ? io1 : io2);
  const int bn = blockIdx.x * 128, bm = blockIdx.y * 128;
  const int tid = threadIdx.x;
  const int wave = tid >> 6, lane = tid & 63;
  const int l16 = lane & 15, quad = lane >> 4;
  const int wm = (wave >> 1) * 64, wn = (wave & 1) * 64;
  const int arow = bm + wm + l16;
  const int brow = bn + wn + l16;

  f32x4 acc[4][4] = {};

  for (int kt = 0; kt < K; kt += 32) {
    const int koff = kt + quad * 8;
    bf16x8 a_h[4], b_h[4], a_l[4], b_l[4];
#pragma unroll
    for (int mt = 0; mt < 4; ++mt)
      a_h[mt] = *(const bf16x8*)(Ah + (size_t)(arow + mt * 16) * K + koff);
#pragma unroll
    for (int nt = 0; nt < 4; ++nt)
      b_h[nt] = *(const bf16x8*)(io.Bh + (size_t)(brow + nt * 16) * K + koff);
    if (SPLIT) {
#pragma unroll
      for (int mt = 0; mt < 4; ++mt)
        a_l[mt] = *(const bf16x8*)(Al + (size_t)(arow + mt * 16) * K + koff);
#pragma unroll
      for (int nt = 0; nt < 4; ++nt)
        b_l[nt] = *(const bf16x8*)(io.Bl + (size_t)(brow + nt * 16) * K + koff);
    }
#pragma unroll
    for (int mt = 0; mt < 4; ++mt)
#pragma unroll
      for (int nt = 0; nt < 4; ++nt) {
        acc[mt][nt] = __builtin_amdgcn_mfma_f32_16x16x32_bf16(a_h[mt], b_h[nt], acc[mt][nt], 0, 0, 0);
        if (SPLIT) {
          acc[mt][nt] = __builtin_amdgcn_mfma_f32_16x16x32_bf16(a_h[mt], b_l[nt], acc[mt][nt], 0, 0, 0);
          acc[mt][nt] = __builtin_amdgcn_mfma_f32_16x16x32_bf16(a_l[mt], b_h[nt], acc[mt][nt], 0, 0, 0);
        }
      }
  }

  // Epilogue. C/D layout: col = lane&15, row = quad*4 + reg  [m89-verified]
#pragma unroll
  for (int mt = 0; mt < 4; ++mt)
#pragma unroll
    for (int nt = 0; nt < 4; ++nt) {
      int col = bn + wn + nt * 16 + l16;
      float bv = io.bias ? io.bias[col] : 0.f;
#pragma unroll
      for (int r = 0; r < 4; ++r) {
        int row = bm + wm + mt * 16 + quad * 4 + r;
        float v = acc[mt][nt][r] + bv;
        if (RELU) v = fmaxf(v, 0.f);
        size_t oidx = (size_t)row * N + col;
        if (io.Cf) io.Cf[oidx] = v;
        if (io.Ch) {
          u16 h = f2bf(v);
          io.Ch[oidx] = h;
          if (io.Cl) io.Cl[oidx] = f2bf(v - bf2f(h));
        }
      }
    }
}

// ---------------- flash attention, split-K, no-max softmax ----------------
// Grid (64 qblocks, 2 key-chunks, 8 heads) = 1024 blocks, 4 waves each ->
// 16 waves/CU. Logits bounded (max ~45 << 88) so exp2 cannot overflow fp32:
// p = exp2(s*log2e) unnormalized, masked lanes -> p = 0, l accumulated
// per-lane and reduced once at the end. No barriers (P LDS is wave-private;
// same-wave RAW ordered by compiler-inserted lgkmcnt). Partial O (fp32,
// unnormalized) + l per (qrow, chunk, head) written to scratch; combine
// kernel normalizes.
__global__ __launch_bounds__(256) void attn(const u16* __restrict__ Qh, const u16* __restrict__ Ql,
                                            const u16* __restrict__ Kh, const u16* __restrict__ Kl,
                                            const u16* __restrict__ Vt, const u32* __restrict__ mb,
                                            float* __restrict__ O0, float* __restrict__ O1,
                                            float* __restrict__ lp) {
  const int S = 4096, D = 512;
  const float L2E = 1.44269504088896340736f;
  const int h = blockIdx.z, chunk = blockIdx.y;
  const int tid = threadIdx.x, wave = tid >> 6, lane = tid & 63;
  const int l16 = lane & 15, quad = lane >> 4;
  const int q0 = blockIdx.x * 64 + wave * 16;
  const int kbeg = chunk * 2048, kend = kbeg + 2048;

  __shared__ u16 Pl[4][16 * 34];       // row stride 34 u16: write conflicts <=2-way (free)
  u16* myP = &Pl[wave][0];

  bf16x8 qh[2], ql[2];
  {
    size_t qb = (size_t)(q0 + l16) * D + h * 64 + quad * 8;
    qh[0] = *(const bf16x8*)(Qh + qb); qh[1] = *(const bf16x8*)(Qh + qb + 32);
    ql[0] = *(const bf16x8*)(Ql + qb); ql[1] = *(const bf16x8*)(Ql + qb + 32);
  }

  float l_lane[4] = {0.f, 0.f, 0.f, 0.f};
  f32x4 accO[4] = {};

  for (int kt = kbeg; kt < kend; kt += 32) {
    f32x4 sc[2] = {};
#pragma unroll
    for (int st = 0; st < 2; ++st) {
      size_t kb = (size_t)(kt + st * 16 + l16) * D + h * 64 + quad * 8;
      bf16x8 kh0 = *(const bf16x8*)(Kh + kb), kh1 = *(const bf16x8*)(Kh + kb + 32);
      bf16x8 kl0 = *(const bf16x8*)(Kl + kb), kl1 = *(const bf16x8*)(Kl + kb + 32);
      sc[st] = __builtin_amdgcn_mfma_f32_16x16x32_bf16(qh[0], kh0, sc[st], 0, 0, 0);
      sc[st] = __builtin_amdgcn_mfma_f32_16x16x32_bf16(qh[1], kh1, sc[st], 0, 0, 0);
      sc[st] = __builtin_amdgcn_mfma_f32_16x16x32_bf16(qh[0], kl0, sc[st], 0, 0, 0);
      sc[st] = __builtin_amdgcn_mfma_f32_16x16x32_bf16(qh[1], kl1, sc[st], 0, 0, 0);
      sc[st] = __builtin_amdgcn_mfma_f32_16x16x32_bf16(ql[0], kh0, sc[st], 0, 0, 0);
      sc[st] = __builtin_amdgcn_mfma_f32_16x16x32_bf16(ql[1], kh1, sc[st], 0, 0, 0);
    }
    u32 words[4];
#pragma unroll
    for (int r = 0; r < 4; ++r)
      words[r] = mb[(size_t)(q0 + quad * 4 + r) * 128 + (kt >> 5)];
#pragma unroll
    for (int st = 0; st < 2; ++st)
#pragma unroll
      for (int r = 0; r < 4; ++r) {
        bool keep = (words[r] >> (st * 16 + l16)) & 1u;
        float p = keep ? exp2f(sc[st][r] * L2E) : 0.f;
        l_lane[r] += p;
        myP[(quad * 4 + r) * 34 + st * 16 + l16] = f2bf_trunc(p);
      }
    // same-wave LDS RAW: compiler orders via lgkmcnt; no barrier needed
    bf16x8 pf = *(const bf16x8*)(myP + l16 * 34 + quad * 8);
#pragma unroll
    for (int nt = 0; nt < 4; ++nt) {
      bf16x8 vf = *(const bf16x8*)(Vt + (size_t)(h * 64 + nt * 16 + l16) * S + kt + quad * 8);
      accO[nt] = __builtin_amdgcn_mfma_f32_16x16x32_bf16(pf, vf, accO[nt], 0, 0, 0);
    }
  }

  // reduce l over the 16 lanes of each row (xor 1,2,4,8 stays within quad group)
#pragma unroll
  for (int r = 0; r < 4; ++r) {
    float s = l_lane[r];
    s += __shfl_xor(s, 1);
    s += __shfl_xor(s, 2);
    s += __shfl_xor(s, 4);
    s += __shfl_xor(s, 8);
    l_lane[r] = s;
  }
  float* Op = chunk ? O1 : O0;
#pragma unroll
  for (int nt = 0; nt < 4; ++nt)
#pragma unroll
    for (int r = 0; r < 4; ++r) {
      int row = q0 + quad * 4 + r;
      Op[((size_t)h * S + row) * 64 + nt * 16 + l16] = accO[nt][r];
    }
  if (l16 == 0)
#pragma unroll
    for (int r = 0; r < 4; ++r)
      lp[((size_t)h * 2 + chunk) * S + q0 + quad * 4 + r] = l_lane[r];
}

// ---------------- combine split-K partials -> ctx (bf16) ----------------
__global__ __launch_bounds__(256) void attn_combine(const float* __restrict__ O0,
                                                    const float* __restrict__ O1,
                                                    const float* __restrict__ lp,
                                                    u16* __restrict__ ctx) {
  const int S = 4096;
  int i = (blockIdx.x * 256 + threadIdx.x);       // over S*D/4 groups of 4
  int row = i >> 7;                                // 128 groups per row
  int col4 = (i & 127) * 4;
  int h = col4 >> 6, c = col4 & 63;
  size_t ob = ((size_t)h * S + row) * 64 + c;
  f32x4 o = *(const f32x4*)(O0 + ob) + *(const f32x4*)(O1 + ob);
  float l = lp[((size_t)h * 2 + 0) * S + row] + lp[((size_t)h * 2 + 1) * S + row];
  float rl = 1.f / l;
  u16x4 out;
#pragma unroll
  for (int j = 0; j < 4; ++j) out[j] = f2bf(o[j] * rl);
  *(u16x4*)(ctx + (size_t)row * 512 + col4) = out;
}

// ---------------- residual + layernorm (rows of 512) ----------------
__global__ __launch_bounds__(256) void resid_ln(const float* __restrict__ X,
                                                const float* __restrict__ Y,
                                                const float* __restrict__ g,
                                                const float* __restrict__ b,
                                                float* __restrict__ outF,
                                                u16* __restrict__ outH) {
  int row = blockIdx.x * 4 + (int)(threadIdx.x >> 6);
  int lane = threadIdx.x & 63;
  const float* x0 = X + (size_t)row * 512;
  const float* y0 = Y + (size_t)row * 512;
  int c0 = lane * 4, c1 = 256 + lane * 4;
  f32x4 v0 = *(const f32x4*)(x0 + c0) + *(const f32x4*)(y0 + c0);
  f32x4 v1 = *(const f32x4*)(x0 + c1) + *(const f32x4*)(y0 + c1);
  float s = 0.f, s2 = 0.f;
#pragma unroll
  for (int j = 0; j < 4; ++j) {
    s += v0[j] + v1[j];
    s2 += v0[j] * v0[j] + v1[j] * v1[j];
  }
#pragma unroll
  for (int m = 1; m < 64; m <<= 1) {
    s += __shfl_xor(s, m);
    s2 += __shfl_xor(s2, m);
  }
  float mean = s * (1.f / 512.f);
  float var = s2 * (1.f / 512.f) - mean * mean;
  float rs = rsqrtf(var + 1e-5f);
  f32x4 o0, o1;
#pragma unroll
  for (int j = 0; j < 4; ++j) {
    o0[j] = (v0[j] - mean) * rs * g[c0 + j] + b[c0 + j];
    o1[j] = (v1[j] - mean) * rs * g[c1 + j] + b[c1 + j];
  }
  if (outF) {
    *(f32x4*)(outF + (size_t)row * 512 + c0) = o0;
    *(f32x4*)(outF + (size_t)row * 512 + c1) = o1;
  }
  if (outH) {
    u16x4 h0, h1;
#pragma unroll
    for (int j = 0; j < 4; ++j) { h0[j] = f2bf(o0[j]); h1[j] = f2bf(o1[j]); }
    *(u16x4*)(outH + (size_t)row * 512 + c0) = h0;
    *(u16x4*)(outH + (size_t)row * 512 + c1) = h1;
  }
}

extern "C" void kernel_launch(void* const* d_in, const int* in_sizes, int n_in,
                              void* d_out, int out_size, void* d_ws, size_t ws_size,
                              hipStream_t stream) {
  (void)in_sizes; (void)n_in; (void)out_size; (void)ws_size;
  const float* x   = (const float*)d_in[0];
  const int*   mask= (const int*)d_in[1];
  const float* wq  = (const float*)d_in[2];
  const float* bq  = (const float*)d_in[3];
  const float* wk  = (const float*)d_in[4];
  const float* bk  = (const float*)d_in[5];
  const float* wv  = (const float*)d_in[6];
  const float* bv  = (const float*)d_in[7];
  const float* wo  = (const float*)d_in[8];
  const float* bo  = (const float*)d_in[9];
  const float* w1  = (const float*)d_in[10];
  const float* b1  = (const float*)d_in[11];
  const float* w2  = (const float*)d_in[12];
  const float* b2  = (const float*)d_in[13];
  const float* g1  = (const float*)d_in[14];
  const float* be1 = (const float*)d_in[15];
  const float* g2  = (const float*)d_in[16];
  const float* be2 = (const float*)d_in[17];

  const int S = 4096, D = 512, F = 2048;
  char* ws = (char*)d_ws;
  size_t cur = 0;
  auto alloc = [&](size_t bytes) {
    char* p = ws + cur;
    cur += (bytes + 255) & ~(size_t)255;
    return p;
  };
  // persistent weight region (bf16, transposed to N x K)
  u16* wqT_h = (u16*)alloc((size_t)D * D * 2); u16* wqT_l = (u16*)alloc((size_t)D * D * 2);
  u16* wkT_h = (u16*)alloc((size_t)D * D * 2); u16* wkT_l = (u16*)alloc((size_t)D * D * 2);
  u16* wvT_h = (u16*)alloc((size_t)D * D * 2); u16* wvT_l = (u16*)alloc((size_t)D * D * 2);
  u16* woT_h = (u16*)alloc((size_t)D * D * 2); u16* woT_l = (u16*)alloc((size_t)D * D * 2);
  u16* w1T_h = (u16*)alloc((size_t)D * F * 2); u16* w1T_l = (u16*)alloc((size_t)D * F * 2);
  u16* w2T_h = (u16*)alloc((size_t)D * F * 2); u16* w2T_l = (u16*)alloc((size_t)D * F * 2);
  u32* mbits = (u32*)alloc((size_t)S * S / 8);
  u16* xh = (u16*)alloc((size_t)S * D * 2);
  u16* xl = (u16*)alloc((size_t)S * D * 2);
  u16* Qh = (u16*)alloc((size_t)S * D * 2);
  u16* Ql = (u16*)alloc((size_t)S * D * 2);
  u16* Kh = (u16*)alloc((size_t)S * D * 2);
  u16* Kl = (u16*)alloc((size_t)S * D * 2);
  u16* Vh = (u16*)alloc((size_t)S * D * 2);
  u16* Vt = (u16*)alloc((size_t)S * D * 2);
  u16* ctx = (u16*)alloc((size_t)S * D * 2);
  float* x1 = (float*)alloc((size_t)S * D * 4);
  u16* x1h = (u16*)alloc((size_t)S * D * 2);
  // aliased regions (lifetimes disjoint by stream order):
  float* proj = (float*)xh;   // 8 MB over xh+xl; written by out-proj AFTER combine read O0
  u16* hbuf = Qh;             // 16 MB over Qh..Kl; written after attention
  float* ff2 = (float*)Vh;    // 8 MB over Vh+Vt; written after attention
  // attention split-K partials, aliased onto dead regions:
  //  O0 (8 MB: 8 heads x 4096 x 64 fp32) -> xh+xl   (dead after QKV gemm)
  //  O1 (8 MB)                            -> x1      (written later by resid_ln, after combine)
  //  lp (256 KB)                          -> x1h     (written later by resid_ln)
  float* O0 = (float*)xh;
  float* O1 = x1;
  float* lp = (float*)x1h;

  GemmIO ioQ = {wqT_h, wqT_l, bq, nullptr, Qh, Ql};
  GemmIO ioK = {wkT_h, wkT_l, bk, nullptr, Kh, Kl};
  GemmIO ioV = {wvT_h, wvT_l, bv, nullptr, Vh, nullptr};
  GemmIO ioP = {woT_h, nullptr, bo, proj, nullptr, nullptr};
  GemmIO io1 = {w1T_h, nullptr, b1, nullptr, hbuf, nullptr};
  GemmIO io2 = {w2T_h, nullptr, b2, ff2, nullptr, nullptr};

  dim3 tb(32, 8);
  // 1. converts
  convert_split<<<(S * D) / 1024, 256, 0, stream>>>(x, xh, xl);
  pack_mask<<<(S * S) / 256, 256, 0, stream>>>(mask, (unsigned long long*)mbits);
  wtrans<<<dim3(16, 16), tb, 0, stream>>>(wq, wqT_h, wqT_l, D, D);
  wtrans<<<dim3(16, 16), tb, 0, stream>>>(wk, wkT_h, wkT_l, D, D);
  wtrans<<<dim3(16, 16), tb, 0, stream>>>(wv, wvT_h, wvT_l, D, D);
  wtrans<<<dim3(16, 16), tb, 0, stream>>>(wo, woT_h, woT_l, D, D);
  wtrans<<<dim3(64, 16), tb, 0, stream>>>(w1, w1T_h, w1T_l, D, F);
  wtrans<<<dim3(16, 64), tb, 0, stream>>>(w2, w2T_h, w2T_l, F, D);
  // 2. QKV projections (split for accurate logits downstream)
  gemm_bt<1, 0><<<dim3(4, 32, 3), 256, 0, stream>>>(xh, xl, ioQ, ioK, ioV, S, D, D);
  // 3. V -> V^T (Dh-major) for PV B-fragments
  transpose_u16<<<dim3(16, 128), tb, 0, stream>>>(Vh, Vt, S, D);
  // 4. flash attention (split-K over 2 key chunks) + combine
  attn<<<dim3(64, 2, 8), 256, 0, stream>>>(Qh, Ql, Kh, Kl, Vt, mbits, O0, O1, lp);
  attn_combine<<<(S * D / 4) / 256, 256, 0, stream>>>(O0, O1, lp, ctx);
  // 5. output projection
  gemm_bt<0, 0><<<dim3(4, 32, 1), 256, 0, stream>>>(ctx, nullptr, ioP, ioP, ioP, S, D, D);
  // 6. residual + LN1
  resid_ln<<<S / 4, 256, 0, stream>>>(x, proj, g1, be1, x1, x1h);
  // 7. FFN
  gemm_bt<0, 1><<<dim3(16, 32, 1), 256, 0, stream>>>(x1h, nullptr, io1, io1, io1, S, F, D);
  gemm_bt<0, 0><<<dim3(4, 32, 1), 256, 0, stream>>>(hbuf, nullptr, io2, io2, io2, S, D, F);
  // 8. residual + LN2 -> final fp32 output
  resid_ln<<<S / 4, 256, 0, stream>>>(x1, ff2, g2, be2, (float*)d_out, nullptr);
}

// Round 3
// 482.082 us; speedup vs baseline: 1.6822x; 1.5016x over previous
//
#include <hip/hip_runtime.h>

typedef unsigned short u16;
typedef unsigned int u32;
typedef unsigned long long u64;
typedef __attribute__((ext_vector_type(4))) float f32x4;
typedef __attribute__((ext_vector_type(8))) short bf16x8;   // 8 bf16 (4 VGPRs)
typedef __attribute__((ext_vector_type(4))) u16 u16x4;

#define DEV __device__ __forceinline__

DEV u16 f2bf(float f) {               // RNE fp32 -> bf16
  union { float f; u32 u; } c; c.f = f;
  u32 u = c.u;
  u += 0x7fffu + ((u >> 16) & 1u);
  return (u16)(u >> 16);
}
DEV float bf2f(u16 h) {
  union { u32 u; float f; } c; c.u = ((u32)h) << 16;
  return c.f;
}
DEV u16 f2bf_trunc(float f) {         // truncating pack (p>=0; softmax normalizes the bias)
  union { float f; u32 u; } c; c.f = f;
  return (u16)(c.u >> 16);
}

// async global->LDS, 16B per lane. Dest is WAVE-UNIFORM base + lane*16 (m104/m108).
DEV void gload_lds16(const void* g, void* l) {
  __builtin_amdgcn_global_load_lds(
      (const __attribute__((address_space(1))) u32*)(u64)g,
      (__attribute__((address_space(3))) u32*)(u32)(u64)l,   // low 32 bits = LDS offset
      16, 0, 0);
}

// ---------------- elementwise fp32 -> bf16 hi/lo split ----------------
__global__ __launch_bounds__(256) void convert_split(const float* __restrict__ in,
                                                     u16* __restrict__ hi,
                                                     u16* __restrict__ lo) {
  int i = (blockIdx.x * 256 + threadIdx.x) * 4;
  f32x4 v = *(const f32x4*)(in + i);
  u16x4 h, l;
#pragma unroll
  for (int j = 0; j < 4; ++j) {
    h[j] = f2bf(v[j]);
    l[j] = f2bf(v[j] - bf2f(h[j]));
  }
  *(u16x4*)(hi + i) = h;
  *(u16x4*)(lo + i) = l;
}

// ---------------- mask (S,S) int32 -> bitmask (1 bit per entry) ----------------
__global__ __launch_bounds__(256) void pack_mask(const int* __restrict__ m,
                                                 unsigned long long* __restrict__ out) {
  size_t i = (size_t)blockIdx.x * 256 + threadIdx.x;
  unsigned long long b = __ballot(m[i] != 0);
  if ((threadIdx.x & 63) == 0) out[i >> 6] = b;
}

// ---------------- fp32 weight (R,C) -> transposed bf16 hi/lo (C,R) ----------------
__global__ void wtrans(const float* __restrict__ W, u16* __restrict__ Th,
                       u16* __restrict__ Tl, int R, int C) {
  __shared__ float t[32][33];
  int c0 = blockIdx.x * 32, r0 = blockIdx.y * 32;
  int tx = threadIdx.x, ty = threadIdx.y;  // (32,8)
#pragma unroll
  for (int i = 0; i < 4; ++i)
    t[ty + 8 * i][tx] = W[(size_t)(r0 + ty + 8 * i) * C + c0 + tx];
  __syncthreads();
#pragma unroll
  for (int i = 0; i < 4; ++i) {
    float v = t[tx][ty + 8 * i];
    u16 h = f2bf(v);
    size_t o = (size_t)(c0 + ty + 8 * i) * R + r0 + tx;
    Th[o] = h;
    Tl[o] = f2bf(v - bf2f(h));
  }
}

// ---------------- u16 transpose (R,C) -> (C,R) ----------------
__global__ void transpose_u16(const u16* __restrict__ in, u16* __restrict__ out,
                              int R, int C) {
  __shared__ u16 t[32][33];
  int c0 = blockIdx.x * 32, r0 = blockIdx.y * 32;
  int tx = threadIdx.x, ty = threadIdx.y;  // (32,8)
#pragma unroll
  for (int i = 0; i < 4; ++i)
    t[ty + 8 * i][tx] = in[(size_t)(r0 + ty + 8 * i) * C + c0 + tx];
  __syncthreads();
#pragma unroll
  for (int i = 0; i < 4; ++i)
    out[(size_t)(c0 + ty + 8 * i) * R + r0 + tx] = t[tx][ty + 8 * i];
}

// ---------------- GEMM: C[M,N] = A[M,K] @ B^T[N,K] + bias ----------------
struct GemmIO {
  const u16* Bh; const u16* Bl; const float* bias;
  float* Cf; u16* Ch; u16* Cl;
};

template <int SPLIT, int RELU>
__global__ __launch_bounds__(256) void gemm_bt(const u16* __restrict__ Ah,
                                               const u16* __restrict__ Al,
                                               GemmIO io0, GemmIO io1, GemmIO io2,
                                               int M, int N, int K) {
  int z = blockIdx.z;
  GemmIO io = (z == 0) ? io0 : (z == 1 ? io1 : io2);
  const int bn = blockIdx.x * 128, bm = blockIdx.y * 128;
  const int tid = threadIdx.x;
  const int wave = tid >> 6, lane = tid & 63;
  const int l16 = lane & 15, quad = lane >> 4;
  const int wm = (wave >> 1) * 64, wn = (wave & 1) * 64;
  const int arow = bm + wm + l16;
  const int brow = bn + wn + l16;

  f32x4 acc[4][4] = {};

  for (int kt = 0; kt < K; kt += 32) {
    const int koff = kt + quad * 8;
    bf16x8 a_h[4], b_h[4], a_l[4], b_l[4];
#pragma unroll
    for (int mt = 0; mt < 4; ++mt)
      a_h[mt] = *(const bf16x8*)(Ah + (size_t)(arow + mt * 16) * K + koff);
#pragma unroll
    for (int nt = 0; nt < 4; ++nt)
      b_h[nt] = *(const bf16x8*)(io.Bh + (size_t)(brow + nt * 16) * K + koff);
    if (SPLIT) {
#pragma unroll
      for (int mt = 0; mt < 4; ++mt)
        a_l[mt] = *(const bf16x8*)(Al + (size_t)(arow + mt * 16) * K + koff);
#pragma unroll
      for (int nt = 0; nt < 4; ++nt)
        b_l[nt] = *(const bf16x8*)(io.Bl + (size_t)(brow + nt * 16) * K + koff);
    }
#pragma unroll
    for (int mt = 0; mt < 4; ++mt)
#pragma unroll
      for (int nt = 0; nt < 4; ++nt) {
        acc[mt][nt] = __builtin_amdgcn_mfma_f32_16x16x32_bf16(a_h[mt], b_h[nt], acc[mt][nt], 0, 0, 0);
        if (SPLIT) {
          acc[mt][nt] = __builtin_amdgcn_mfma_f32_16x16x32_bf16(a_h[mt], b_l[nt], acc[mt][nt], 0, 0, 0);
          acc[mt][nt] = __builtin_amdgcn_mfma_f32_16x16x32_bf16(a_l[mt], b_h[nt], acc[mt][nt], 0, 0, 0);
        }
      }
  }

  // Epilogue. C/D layout: col = lane&15, row = quad*4 + reg  [m89-verified]
#pragma unroll
  for (int mt = 0; mt < 4; ++mt)
#pragma unroll
    for (int nt = 0; nt < 4; ++nt) {
      int col = bn + wn + nt * 16 + l16;
      float bv = io.bias ? io.bias[col] : 0.f;
#pragma unroll
      for (int r = 0; r < 4; ++r) {
        int row = bm + wm + mt * 16 + quad * 4 + r;
        float v = acc[mt][nt][r] + bv;
        if (RELU) v = fmaxf(v, 0.f);
        size_t oidx = (size_t)row * N + col;
        if (io.Cf) io.Cf[oidx] = v;
        if (io.Ch) {
          u16 h = f2bf(v);
          io.Ch[oidx] = h;
          if (io.Cl) io.Cl[oidx] = f2bf(v - bf2f(h));
        }
      }
    }
}

// ---------------- flash attention, split-K, LDS-staged K/V ----------------
// Grid (16 head*chunk, 64 qblocks): bid%8 = hc%8 so blocks sharing (h,chunk)
// likely co-locate per XCD -> K/V working set ~2.5MB fits per-XCD L2.
// Per 32-key iteration the block cooperatively stages Kh/Kl (8KB) + V (4KB)
// into LDS via global_load_lds (3 x 1KB per wave) -- kills the 4x per-wave
// redundant L2/L3 fragment reads that bounded round 2. XOR-swizzled LDS
// placement (chosen via the per-lane *global* source address; dest is
// lane-contiguous) keeps fragment ds_read_b128 at 2-way bank alias (free).
__global__ __launch_bounds__(256) void attn(const u16* __restrict__ Qh, const u16* __restrict__ Ql,
                                            const u16* __restrict__ Kh, const u16* __restrict__ Kl,
                                            const u16* __restrict__ Vt, const u32* __restrict__ mb,
                                            float* __restrict__ O0, float* __restrict__ O1,
                                            float* __restrict__ lp) {
  const int S = 4096, D = 512;
  const float L2E = 1.44269504088896340736f;
  const int h = blockIdx.x >> 1, chunk = blockIdx.x & 1;
  const int tid = threadIdx.x, wave = tid >> 6, lane = tid & 63;
  const int l16 = lane & 15, quad = lane >> 4;
  const int q0 = blockIdx.y * 64 + wave * 16;
  const int kbeg = chunk * 2048;

  // LDS: sKh [32 key][64 dim] 4KB | sKl 4KB | sV [64 dim][32 key] 4KB | P 4x1280B
  __shared__ u16 lds[6144 + 4 * 640];
  u16* sKh = lds;
  u16* sKl = lds + 2048;
  u16* sV  = lds + 4096;
  u16* myP = lds + 6144 + wave * 640;   // stride 40 u16 per q-row (16B-aligned reads)

  // staging sources (per-lane; advance 32 keys per iter)
  const int skey = wave * 8 + (lane >> 3);            // 0..31
  const int kc   = lane & 7;
  const u16* srcKh = Kh + (size_t)(kbeg + skey) * D + h * 64 + ((kc ^ (skey & 7)) * 8);
  const u16* srcKl = Kl + (size_t)(kbeg + skey) * D + h * 64 + ((kc ^ (skey & 7)) * 8);
  const int sdim = wave * 16 + (lane >> 2);           // 0..63
  const int vc   = lane & 3;
  const u16* srcV = Vt + (size_t)(h * 64 + sdim) * S + kbeg + ((vc ^ ((sdim >> 1) & 3)) * 8);
  u16* dstKh = sKh + wave * 512;
  u16* dstKl = sKl + wave * 512;
  u16* dstV  = sV  + wave * 512;

  bf16x8 qh[2], ql[2];
  {
    size_t qb = (size_t)(q0 + l16) * D + h * 64 + quad * 8;
    qh[0] = *(const bf16x8*)(Qh + qb); qh[1] = *(const bf16x8*)(Qh + qb + 32);
    ql[0] = *(const bf16x8*)(Ql + qb); ql[1] = *(const bf16x8*)(Ql + qb + 32);
  }

  float l_lane[4] = {0.f, 0.f, 0.f, 0.f};
  f32x4 accO[4] = {};

  const int ks = l16 & 7;
  const int c0 = (quad ^ ks) * 8;          // chunk slot offset for dims quad*8..
  const int c1 = ((quad ^ 4) ^ ks) * 8;    // ... and dims 32+quad*8..

  for (int it = 0; it < 64; ++it) {
    gload_lds16(srcKh, dstKh);
    gload_lds16(srcKl, dstKl);
    gload_lds16(srcV, dstV);
    srcKh += 32 * D; srcKl += 32 * D; srcV += 32;
    __syncthreads();   // drains vmcnt (global_load_lds) + orders LDS

    const int km = (kbeg >> 5) + it;
    u32 words[4];
#pragma unroll
    for (int r = 0; r < 4; ++r)
      words[r] = mb[(size_t)(q0 + quad * 4 + r) * 128 + km];

    f32x4 sc[2] = {};
#pragma unroll
    for (int st = 0; st < 2; ++st) {
      const u16* rowh = sKh + (st * 16 + l16) * 64;
      const u16* rowl = sKl + (st * 16 + l16) * 64;
      bf16x8 kh0 = *(const bf16x8*)(rowh + c0);
      bf16x8 kh1 = *(const bf16x8*)(rowh + c1);
      bf16x8 kl0 = *(const bf16x8*)(rowl + c0);
      bf16x8 kl1 = *(const bf16x8*)(rowl + c1);
      sc[st] = __builtin_amdgcn_mfma_f32_16x16x32_bf16(qh[0], kh0, sc[st], 0, 0, 0);
      sc[st] = __builtin_amdgcn_mfma_f32_16x16x32_bf16(qh[1], kh1, sc[st], 0, 0, 0);
      sc[st] = __builtin_amdgcn_mfma_f32_16x16x32_bf16(qh[0], kl0, sc[st], 0, 0, 0);
      sc[st] = __builtin_amdgcn_mfma_f32_16x16x32_bf16(qh[1], kl1, sc[st], 0, 0, 0);
      sc[st] = __builtin_amdgcn_mfma_f32_16x16x32_bf16(ql[0], kh0, sc[st], 0, 0, 0);
      sc[st] = __builtin_amdgcn_mfma_f32_16x16x32_bf16(ql[1], kh1, sc[st], 0, 0, 0);
    }
#pragma unroll
    for (int st = 0; st < 2; ++st)
#pragma unroll
      for (int r = 0; r < 4; ++r) {
        bool keep = (words[r] >> (st * 16 + l16)) & 1u;
        float p = keep ? exp2f(sc[st][r] * L2E) : 0.f;
        l_lane[r] += p;
        myP[(quad * 4 + r) * 40 + st * 16 + l16] = f2bf_trunc(p);
      }
    // same-wave LDS RAW (wave-private P): ordered by compiler lgkmcnt
    bf16x8 pf = *(const bf16x8*)(myP + l16 * 40 + quad * 8);
#pragma unroll
    for (int nt = 0; nt < 4; ++nt) {
      int dim = nt * 16 + l16;
      bf16x8 vf = *(const bf16x8*)(sV + dim * 32 + ((quad ^ ((dim >> 1) & 3)) * 8));
      accO[nt] = __builtin_amdgcn_mfma_f32_16x16x32_bf16(pf, vf, accO[nt], 0, 0, 0);
    }
    __syncthreads();   // all waves done reading K/V LDS before next stage
  }

  // reduce l over the 16 lanes of each row
#pragma unroll
  for (int r = 0; r < 4; ++r) {
    float s = l_lane[r];
    s += __shfl_xor(s, 1);
    s += __shfl_xor(s, 2);
    s += __shfl_xor(s, 4);
    s += __shfl_xor(s, 8);
    l_lane[r] = s;
  }
  float* Op = chunk ? O1 : O0;
#pragma unroll
  for (int nt = 0; nt < 4; ++nt)
#pragma unroll
    for (int r = 0; r < 4; ++r) {
      int row = q0 + quad * 4 + r;
      Op[((size_t)h * S + row) * 64 + nt * 16 + l16] = accO[nt][r];
    }
  if (l16 == 0)
#pragma unroll
    for (int r = 0; r < 4; ++r)
      lp[((size_t)h * 2 + chunk) * S + q0 + quad * 4 + r] = l_lane[r];
}

// ---------------- combine split-K partials -> ctx (bf16) ----------------
__global__ __launch_bounds__(256) void attn_combine(const float* __restrict__ O0,
                                                    const float* __restrict__ O1,
                                                    const float* __restrict__ lp,
                                                    u16* __restrict__ ctx) {
  const int S = 4096;
  int i = (blockIdx.x * 256 + threadIdx.x);       // over S*D/4 groups of 4
  int row = i >> 7;                                // 128 groups per row
  int col4 = (i & 127) * 4;
  int h = col4 >> 6, c = col4 & 63;
  size_t ob = ((size_t)h * S + row) * 64 + c;
  f32x4 o = *(const f32x4*)(O0 + ob) + *(const f32x4*)(O1 + ob);
  float l = lp[((size_t)h * 2 + 0) * S + row] + lp[((size_t)h * 2 + 1) * S + row];
  float rl = 1.f / l;
  u16x4 out;
#pragma unroll
  for (int j = 0; j < 4; ++j) out[j] = f2bf(o[j] * rl);
  *(u16x4*)(ctx + (size_t)row * 512 + col4) = out;
}

// ---------------- residual + layernorm (rows of 512) ----------------
__global__ __launch_bounds__(256) void resid_ln(const float* __restrict__ X,
                                                const float* __restrict__ Y,
                                                const float* __restrict__ g,
                                                const float* __restrict__ b,
                                                float* __restrict__ outF,
                                                u16* __restrict__ outH) {
  int row = blockIdx.x * 4 + (int)(threadIdx.x >> 6);
  int lane = threadIdx.x & 63;
  const float* x0 = X + (size_t)row * 512;
  const float* y0 = Y + (size_t)row * 512;
  int c0 = lane * 4, c1 = 256 + lane * 4;
  f32x4 v0 = *(const f32x4*)(x0 + c0) + *(const f32x4*)(y0 + c0);
  f32x4 v1 = *(const f32x4*)(x0 + c1) + *(const f32x4*)(y0 + c1);
  float s = 0.f, s2 = 0.f;
#pragma unroll
  for (int j = 0; j < 4; ++j) {
    s += v0[j] + v1[j];
    s2 += v0[j] * v0[j] + v1[j] * v1[j];
  }
#pragma unroll
  for (int m = 1; m < 64; m <<= 1) {
    s += __shfl_xor(s, m);
    s2 += __shfl_xor(s2, m);
  }
  float mean = s * (1.f / 512.f);
  float var = s2 * (1.f / 512.f) - mean * mean;
  float rs = rsqrtf(var + 1e-5f);
  f32x4 o0, o1;
#pragma unroll
  for (int j = 0; j < 4; ++j) {
    o0[j] = (v0[j] - mean) * rs * g[c0 + j] + b[c0 + j];
    o1[j] = (v1[j] - mean) * rs * g[c1 + j] + b[c1 + j];
  }
  if (outF) {
    *(f32x4*)(outF + (size_t)row * 512 + c0) = o0;
    *(f32x4*)(outF + (size_t)row * 512 + c1) = o1;
  }
  if (outH) {
    u16x4 h0, h1;
#pragma unroll
    for (int j = 0; j < 4; ++j) { h0[j] = f2bf(o0[j]); h1[j] = f2bf(o1[j]); }
    *(u16x4*)(outH + (size_t)row * 512 + c0) = h0;
    *(u16x4*)(outH + (size_t)row * 512 + c1) = h1;
  }
}

extern "C" void kernel_launch(void* const* d_in, const int* in_sizes, int n_in,
                              void* d_out, int out_size, void* d_ws, size_t ws_size,
                              hipStream_t stream) {
  (void)in_sizes; (void)n_in; (void)out_size; (void)ws_size;
  const float* x   = (const float*)d_in[0];
  const int*   mask= (const int*)d_in[1];
  const float* wq  = (const float*)d_in[2];
  const float* bq  = (const float*)d_in[3];
  const float* wk  = (const float*)d_in[4];
  const float* bk  = (const float*)d_in[5];
  const float* wv  = (const float*)d_in[6];
  const float* bv  = (const float*)d_in[7];
  const float* wo  = (const float*)d_in[8];
  const float* bo  = (const float*)d_in[9];
  const float* w1  = (const float*)d_in[10];
  const float* b1  = (const float*)d_in[11];
  const float* w2  = (const float*)d_in[12];
  const float* b2  = (const float*)d_in[13];
  const float* g1  = (const float*)d_in[14];
  const float* be1 = (const float*)d_in[15];
  const float* g2  = (const float*)d_in[16];
  const float* be2 = (const float*)d_in[17];

  const int S = 4096, D = 512, F = 2048;
  char* ws = (char*)d_ws;
  size_t cur = 0;
  auto alloc = [&](size_t bytes) {
    char* p = ws + cur;
    cur += (bytes + 255) & ~(size_t)255;
    return p;
  };
  // persistent weight region (bf16, transposed to N x K)
  u16* wqT_h = (u16*)alloc((size_t)D * D * 2); u16* wqT_l = (u16*)alloc((size_t)D * D * 2);
  u16* wkT_h = (u16*)alloc((size_t)D * D * 2); u16* wkT_l = (u16*)alloc((size_t)D * D * 2);
  u16* wvT_h = (u16*)alloc((size_t)D * D * 2); u16* wvT_l = (u16*)alloc((size_t)D * D * 2);
  u16* woT_h = (u16*)alloc((size_t)D * D * 2); u16* woT_l = (u16*)alloc((size_t)D * D * 2);
  u16* w1T_h = (u16*)alloc((size_t)D * F * 2); u16* w1T_l = (u16*)alloc((size_t)D * F * 2);
  u16* w2T_h = (u16*)alloc((size_t)D * F * 2); u16* w2T_l = (u16*)alloc((size_t)D * F * 2);
  u32* mbits = (u32*)alloc((size_t)S * S / 8);
  u16* xh = (u16*)alloc((size_t)S * D * 2);
  u16* xl = (u16*)alloc((size_t)S * D * 2);
  u16* Qh = (u16*)alloc((size_t)S * D * 2);
  u16* Ql = (u16*)alloc((size_t)S * D * 2);
  u16* Kh = (u16*)alloc((size_t)S * D * 2);
  u16* Kl = (u16*)alloc((size_t)S * D * 2);
  u16* Vh = (u16*)alloc((size_t)S * D * 2);
  u16* Vt = (u16*)alloc((size_t)S * D * 2);
  u16* ctx = (u16*)alloc((size_t)S * D * 2);
  float* x1 = (float*)alloc((size_t)S * D * 4);
  u16* x1h = (u16*)alloc((size_t)S * D * 2);
  // aliased regions (lifetimes disjoint by stream order):
  float* proj = (float*)xh;   // 8 MB over xh+xl; written by out-proj AFTER combine read O0
  u16* hbuf = Qh;             // 16 MB over Qh..Kl; written after attention
  float* ff2 = (float*)Vh;    // 8 MB over Vh+Vt; written after attention
  float* O0 = (float*)xh;     // 8 MB partials chunk 0 (xh+xl dead after QKV gemm)
  float* O1 = x1;             // 8 MB partials chunk 1 (x1 written later by resid_ln)
  float* lp = (float*)x1h;    // 256 KB (x1h written later by resid_ln)

  GemmIO ioQ = {wqT_h, wqT_l, bq, nullptr, Qh, Ql};
  GemmIO ioK = {wkT_h, wkT_l, bk, nullptr, Kh, Kl};
  GemmIO ioV = {wvT_h, wvT_l, bv, nullptr, Vh, nullptr};
  GemmIO ioP = {woT_h, nullptr, bo, proj, nullptr, nullptr};
  GemmIO io1 = {w1T_h, nullptr, b1, nullptr, hbuf, nullptr};
  GemmIO io2 = {w2T_h, nullptr, b2, ff2, nullptr, nullptr};

  dim3 tb(32, 8);
  // 1. converts
  convert_split<<<(S * D) / 1024, 256, 0, stream>>>(x, xh, xl);
  pack_mask<<<(S * S) / 256, 256, 0, stream>>>(mask, (unsigned long long*)mbits);
  wtrans<<<dim3(16, 16), tb, 0, stream>>>(wq, wqT_h, wqT_l, D, D);
  wtrans<<<dim3(16, 16), tb, 0, stream>>>(wk, wkT_h, wkT_l, D, D);
  wtrans<<<dim3(16, 16), tb, 0, stream>>>(wv, wvT_h, wvT_l, D, D);
  wtrans<<<dim3(16, 16), tb, 0, stream>>>(wo, woT_h, woT_l, D, D);
  wtrans<<<dim3(64, 16), tb, 0, stream>>>(w1, w1T_h, w1T_l, D, F);
  wtrans<<<dim3(16, 64), tb, 0, stream>>>(w2, w2T_h, w2T_l, F, D);
  // 2. QKV projections (split for accurate logits downstream)
  gemm_bt<1, 0><<<dim3(4, 32, 3), 256, 0, stream>>>(xh, xl, ioQ, ioK, ioV, S, D, D);
  // 3. V -> V^T (Dh-major) for PV B-fragments
  transpose_u16<<<dim3(16, 128), tb, 0, stream>>>(Vh, Vt, S, D);
  // 4. flash attention (split-K over 2 key chunks, LDS-staged) + combine
  attn<<<dim3(16, 64), 256, 0, stream>>>(Qh, Ql, Kh, Kl, Vt, mbits, O0, O1, lp);
  attn_combine<<<(S * D / 4) / 256, 256, 0, stream>>>(O0, O1, lp, ctx);
  // 5. output projection
  gemm_bt<0, 0><<<dim3(4, 32, 1), 256, 0, stream>>>(ctx, nullptr, ioP, ioP, ioP, S, D, D);
  // 6. residual + LN1
  resid_ln<<<S / 4, 256, 0, stream>>>(x, proj, g1, be1, x1, x1h);
  // 7. FFN
  gemm_bt<0, 1><<<dim3(16, 32, 1), 256, 0, stream>>>(x1h, nullptr, io1, io1, io1, S, F, D);
  gemm_bt<0, 0><<<dim3(4, 32, 1), 256, 0, stream>>>(hbuf, nullptr, io2, io2, io2, S, D, F);
  // 8. residual + LN2 -> final fp32 output
  resid_ln<<<S / 4, 256, 0, stream>>>(x1, ff2, g2, be2, (float*)d_out, nullptr);
}

// Round 4
// 461.732 us; speedup vs baseline: 1.7564x; 1.0441x over previous
//
#include <hip/hip_runtime.h>

typedef unsigned short u16;
typedef unsigned int u32;
typedef unsigned long long u64;
typedef __attribute__((ext_vector_type(4))) float f32x4;
typedef __attribute__((ext_vector_type(8))) short bf16x8;   // 8 bf16 (4 VGPRs)
typedef __attribute__((ext_vector_type(4))) u16 u16x4;

#define DEV __device__ __forceinline__

DEV u16 f2bf(float f) {               // RNE fp32 -> bf16
  union { float f; u32 u; } c; c.f = f;
  u32 u = c.u;
  u += 0x7fffu + ((u >> 16) & 1u);
  return (u16)(u >> 16);
}
DEV float bf2f(u16 h) {
  union { u32 u; float f; } c; c.u = ((u32)h) << 16;
  return c.f;
}
DEV u16 f2bf_trunc(float f) {         // truncating pack (p>=0; softmax normalizes the bias)
  union { float f; u32 u; } c; c.f = f;
  return (u16)(c.u >> 16);
}

// async global->LDS, 16B per lane. Dest is WAVE-UNIFORM base + lane*16 (m104/m108).
DEV void gload_lds16(const void* g, void* l) {
  __builtin_amdgcn_global_load_lds(
      (const __attribute__((address_space(1))) u32*)(u64)g,
      (__attribute__((address_space(3))) u32*)(u32)(u64)l,   // low 32 bits = LDS offset
      16, 0, 0);
}

// ---------------- elementwise fp32 -> bf16 hi/lo split ----------------
__global__ __launch_bounds__(256) void convert_split(const float* __restrict__ in,
                                                     u16* __restrict__ hi,
                                                     u16* __restrict__ lo) {
  int i = (blockIdx.x * 256 + threadIdx.x) * 4;
  f32x4 v = *(const f32x4*)(in + i);
  u16x4 h, l;
#pragma unroll
  for (int j = 0; j < 4; ++j) {
    h[j] = f2bf(v[j]);
    l[j] = f2bf(v[j] - bf2f(h[j]));
  }
  *(u16x4*)(hi + i) = h;
  *(u16x4*)(lo + i) = l;
}

// ---------------- pack fp32 Q/K -> bf16 hi/lo ----------------
__global__ __launch_bounds__(256) void pack_qk(const float* __restrict__ Qf,
                                               const float* __restrict__ Kf,
                                               u16* __restrict__ Qh, u16* __restrict__ Ql,
                                               u16* __restrict__ Kh, u16* __restrict__ Kl) {
  int i = (blockIdx.x * 256 + threadIdx.x) * 4;
  f32x4 q = *(const f32x4*)(Qf + i);
  f32x4 k = *(const f32x4*)(Kf + i);
  u16x4 qh, ql, kh, kl;
#pragma unroll
  for (int j = 0; j < 4; ++j) {
    qh[j] = f2bf(q[j]); ql[j] = f2bf(q[j] - bf2f(qh[j]));
    kh[j] = f2bf(k[j]); kl[j] = f2bf(k[j] - bf2f(kh[j]));
  }
  *(u16x4*)(Qh + i) = qh; *(u16x4*)(Ql + i) = ql;
  *(u16x4*)(Kh + i) = kh; *(u16x4*)(Kl + i) = kl;
}

// ---------------- mask (S,S) int32 -> bitmask (1 bit per entry) ----------------
__global__ __launch_bounds__(256) void pack_mask(const int* __restrict__ m,
                                                 unsigned long long* __restrict__ out) {
  size_t i = (size_t)blockIdx.x * 256 + threadIdx.x;
  unsigned long long b = __ballot(m[i] != 0);
  if ((threadIdx.x & 63) == 0) out[i >> 6] = b;
}

// ---------------- fp32 weight (R,C) -> transposed bf16 hi/lo (C,R) ----------------
struct W4 { const float* w[4]; u16* th[4]; u16* tl[4]; };

template <int NZ>
__global__ void wtrans(W4 p, int R, int C) {
  const float* __restrict__ W = p.w[NZ == 1 ? 0 : blockIdx.z];
  u16* __restrict__ Th = p.th[NZ == 1 ? 0 : blockIdx.z];
  u16* __restrict__ Tl = p.tl[NZ == 1 ? 0 : blockIdx.z];
  __shared__ float t[32][33];
  int c0 = blockIdx.x * 32, r0 = blockIdx.y * 32;
  int tx = threadIdx.x, ty = threadIdx.y;  // (32,8)
#pragma unroll
  for (int i = 0; i < 4; ++i)
    t[ty + 8 * i][tx] = W[(size_t)(r0 + ty + 8 * i) * C + c0 + tx];
  __syncthreads();
#pragma unroll
  for (int i = 0; i < 4; ++i) {
    float v = t[tx][ty + 8 * i];
    u16 h = f2bf(v);
    size_t o = (size_t)(c0 + ty + 8 * i) * R + r0 + tx;
    Th[o] = h;
    Tl[o] = f2bf(v - bf2f(h));
  }
}

// ---------------- fp32 (R,C) -> transposed bf16 (C,R) (for V -> Vt) ----------------
__global__ void transpose_f32_bf16(const float* __restrict__ in, u16* __restrict__ out,
                                   int R, int C) {
  __shared__ float t[32][33];
  int c0 = blockIdx.x * 32, r0 = blockIdx.y * 32;
  int tx = threadIdx.x, ty = threadIdx.y;  // (32,8)
#pragma unroll
  for (int i = 0; i < 4; ++i)
    t[ty + 8 * i][tx] = in[(size_t)(r0 + ty + 8 * i) * C + c0 + tx];
  __syncthreads();
#pragma unroll
  for (int i = 0; i < 4; ++i)
    out[(size_t)(c0 + ty + 8 * i) * R + r0 + tx] = f2bf(t[tx][ty + 8 * i]);
}

// ---------------- staged GEMM: C[M,N] = A[M,K] @ B^T[N,K] + bias ----------------
// m97 structure: 128x128 tile, BK=32, global_load_lds width=16 staging, 2-barrier
// K-loop, ds_read_b128 fragments. NSPLIT>1: split-K, fp32 atomicAdd partials
// (bias added by split 0 only; output must be pre-zeroed).
struct GemmIO {
  const u16* Bh; const u16* Bl; const float* bias;
  float* Cf; u16* Ch; u16* Cl;
};

template <int SPLIT, int RELU, int NSPLIT>
__global__ __launch_bounds__(256) void gemm_bt(const u16* __restrict__ Ah,
                                               const u16* __restrict__ Al,
                                               GemmIO io0, GemmIO io1, GemmIO io2,
                                               int M, int N, int K) {
  const int z = blockIdx.z;
  const int mat = z / NSPLIT, ks = z % NSPLIT;
  GemmIO io = (mat == 0) ? io0 : (mat == 1 ? io1 : io2);
  const int kchunk = K / NSPLIT;
  const int kbeg = ks * kchunk, kend = kbeg + kchunk;
  const int bn = blockIdx.x * 128, bm = blockIdx.y * 128;
  const int tid = threadIdx.x;
  const int wave = tid >> 6, lane = tid & 63;
  const int l16 = lane & 15, quad = lane >> 4;
  const int wm = (wave >> 1) * 64, wn = (wave & 1) * 64;

  __shared__ u16 sA[128 * 32];
  __shared__ u16 sB[128 * 32];
  __shared__ u16 sAl[SPLIT ? 128 * 32 : 1];
  __shared__ u16 sBl[SPLIT ? 128 * 32 : 1];

  // staging: each wave stages 32 rows per tile (2 x gload16); lane covers
  // row = wave*32 + half*16 + lane/4, cols (lane%4)*8.. (16B)
  const int srow = wave * 32 + (lane >> 2);
  const int scol = (lane & 3) * 8;
  const u16* srcA0 = Ah + (size_t)(bm + srow) * K + kbeg + scol;
  const u16* srcB0 = io.Bh + (size_t)(bn + srow) * K + kbeg + scol;
  const size_t half_off = (size_t)16 * K;
  u16* dstA = sA + wave * 1024;   // + half*512, lane*8 implicit
  u16* dstB = sB + wave * 1024;
  const u16* srcAl0 = SPLIT ? Al + (size_t)(bm + srow) * K + kbeg + scol : nullptr;
  const u16* srcBl0 = SPLIT ? io.Bl + (size_t)(bn + srow) * K + kbeg + scol : nullptr;

  f32x4 acc[4][4] = {};

  for (int kt = 0; kt < kchunk; kt += 32) {
    gload_lds16(srcA0 + kt, dstA);
    gload_lds16(srcA0 + half_off + kt, dstA + 512);
    gload_lds16(srcB0 + kt, dstB);
    gload_lds16(srcB0 + half_off + kt, dstB + 512);
    if (SPLIT) {
      gload_lds16(srcAl0 + kt, sAl + wave * 1024);
      gload_lds16(srcAl0 + half_off + kt, sAl + wave * 1024 + 512);
      gload_lds16(srcBl0 + kt, sBl + wave * 1024);
      gload_lds16(srcBl0 + half_off + kt, sBl + wave * 1024 + 512);
    }
    __syncthreads();   // drains vmcnt (global_load_lds) + orders LDS

    bf16x8 a_h[4], b_h[4], a_l[4], b_l[4];
#pragma unroll
    for (int mt = 0; mt < 4; ++mt)
      a_h[mt] = *(const bf16x8*)(sA + (wm + mt * 16 + l16) * 32 + quad * 8);
#pragma unroll
    for (int nt = 0; nt < 4; ++nt)
      b_h[nt] = *(const bf16x8*)(sB + (wn + nt * 16 + l16) * 32 + quad * 8);
    if (SPLIT) {
#pragma unroll
      for (int mt = 0; mt < 4; ++mt)
        a_l[mt] = *(const bf16x8*)(sAl + (wm + mt * 16 + l16) * 32 + quad * 8);
#pragma unroll
      for (int nt = 0; nt < 4; ++nt)
        b_l[nt] = *(const bf16x8*)(sBl + (wn + nt * 16 + l16) * 32 + quad * 8);
    }
#pragma unroll
    for (int mt = 0; mt < 4; ++mt)
#pragma unroll
      for (int nt = 0; nt < 4; ++nt) {
        acc[mt][nt] = __builtin_amdgcn_mfma_f32_16x16x32_bf16(a_h[mt], b_h[nt], acc[mt][nt], 0, 0, 0);
        if (SPLIT) {
          acc[mt][nt] = __builtin_amdgcn_mfma_f32_16x16x32_bf16(a_h[mt], b_l[nt], acc[mt][nt], 0, 0, 0);
          acc[mt][nt] = __builtin_amdgcn_mfma_f32_16x16x32_bf16(a_l[mt], b_h[nt], acc[mt][nt], 0, 0, 0);
        }
      }
    __syncthreads();   // all waves done reading before next stage
  }

  // Epilogue. C/D layout: col = lane&15, row = quad*4 + reg  [m89-verified]
#pragma unroll
  for (int mt = 0; mt < 4; ++mt)
#pragma unroll
    for (int nt = 0; nt < 4; ++nt) {
      int col = bn + wn + nt * 16 + l16;
      float bv = (io.bias && (NSPLIT == 1 || ks == 0)) ? io.bias[col] : 0.f;
#pragma unroll
      for (int r = 0; r < 4; ++r) {
        int row = bm + wm + mt * 16 + quad * 4 + r;
        float v = acc[mt][nt][r] + bv;
        size_t oidx = (size_t)row * N + col;
        if (NSPLIT == 1) {
          if (RELU) v = fmaxf(v, 0.f);
          if (io.Cf) io.Cf[oidx] = v;
          if (io.Ch) {
            u16 h = f2bf(v);
            io.Ch[oidx] = h;
            if (io.Cl) io.Cl[oidx] = f2bf(v - bf2f(h));
          }
        } else {
          atomicAdd(&io.Cf[oidx], v);
        }
      }
    }
}

// ---------------- flash attention, split-K, LDS-staged K/V (unchanged r3) ----------------
__global__ __launch_bounds__(256) void attn(const u16* __restrict__ Qh, const u16* __restrict__ Ql,
                                            const u16* __restrict__ Kh, const u16* __restrict__ Kl,
                                            const u16* __restrict__ Vt, const u32* __restrict__ mb,
                                            float* __restrict__ O0, float* __restrict__ O1,
                                            float* __restrict__ lp) {
  const int S = 4096, D = 512;
  const float L2E = 1.44269504088896340736f;
  const int h = blockIdx.x >> 1, chunk = blockIdx.x & 1;
  const int tid = threadIdx.x, wave = tid >> 6, lane = tid & 63;
  const int l16 = lane & 15, quad = lane >> 4;
  const int q0 = blockIdx.y * 64 + wave * 16;
  const int kbeg = chunk * 2048;

  __shared__ u16 lds[6144 + 4 * 640];
  u16* sKh = lds;
  u16* sKl = lds + 2048;
  u16* sV  = lds + 4096;
  u16* myP = lds + 6144 + wave * 640;

  const int skey = wave * 8 + (lane >> 3);
  const int kc   = lane & 7;
  const u16* srcKh = Kh + (size_t)(kbeg + skey) * D + h * 64 + ((kc ^ (skey & 7)) * 8);
  const u16* srcKl = Kl + (size_t)(kbeg + skey) * D + h * 64 + ((kc ^ (skey & 7)) * 8);
  const int sdim = wave * 16 + (lane >> 2);
  const int vc   = lane & 3;
  const u16* srcV = Vt + (size_t)(h * 64 + sdim) * S + kbeg + ((vc ^ ((sdim >> 1) & 3)) * 8);
  u16* dstKh = sKh + wave * 512;
  u16* dstKl = sKl + wave * 512;
  u16* dstV  = sV  + wave * 512;

  bf16x8 qh[2], ql[2];
  {
    size_t qb = (size_t)(q0 + l16) * D + h * 64 + quad * 8;
    qh[0] = *(const bf16x8*)(Qh + qb); qh[1] = *(const bf16x8*)(Qh + qb + 32);
    ql[0] = *(const bf16x8*)(Ql + qb); ql[1] = *(const bf16x8*)(Ql + qb + 32);
  }

  float l_lane[4] = {0.f, 0.f, 0.f, 0.f};
  f32x4 accO[4] = {};

  const int ks = l16 & 7;
  const int c0 = (quad ^ ks) * 8;
  const int c1 = ((quad ^ 4) ^ ks) * 8;

  for (int it = 0; it < 64; ++it) {
    gload_lds16(srcKh, dstKh);
    gload_lds16(srcKl, dstKl);
    gload_lds16(srcV, dstV);
    srcKh += 32 * D; srcKl += 32 * D; srcV += 32;
    __syncthreads();

    const int km = (kbeg >> 5) + it;
    u32 words[4];
#pragma unroll
    for (int r = 0; r < 4; ++r)
      words[r] = mb[(size_t)(q0 + quad * 4 + r) * 128 + km];

    f32x4 sc[2] = {};
#pragma unroll
    for (int st = 0; st < 2; ++st) {
      const u16* rowh = sKh + (st * 16 + l16) * 64;
      const u16* rowl = sKl + (st * 16 + l16) * 64;
      bf16x8 kh0 = *(const bf16x8*)(rowh + c0);
      bf16x8 kh1 = *(const bf16x8*)(rowh + c1);
      bf16x8 kl0 = *(const bf16x8*)(rowl + c0);
      bf16x8 kl1 = *(const bf16x8*)(rowl + c1);
      sc[st] = __builtin_amdgcn_mfma_f32_16x16x32_bf16(qh[0], kh0, sc[st], 0, 0, 0);
      sc[st] = __builtin_amdgcn_mfma_f32_16x16x32_bf16(qh[1], kh1, sc[st], 0, 0, 0);
      sc[st] = __builtin_amdgcn_mfma_f32_16x16x32_bf16(qh[0], kl0, sc[st], 0, 0, 0);
      sc[st] = __builtin_amdgcn_mfma_f32_16x16x32_bf16(qh[1], kl1, sc[st], 0, 0, 0);
      sc[st] = __builtin_amdgcn_mfma_f32_16x16x32_bf16(ql[0], kh0, sc[st], 0, 0, 0);
      sc[st] = __builtin_amdgcn_mfma_f32_16x16x32_bf16(ql[1], kh1, sc[st], 0, 0, 0);
    }
#pragma unroll
    for (int st = 0; st < 2; ++st)
#pragma unroll
      for (int r = 0; r < 4; ++r) {
        bool keep = (words[r] >> (st * 16 + l16)) & 1u;
        float p = keep ? exp2f(sc[st][r] * L2E) : 0.f;
        l_lane[r] += p;
        myP[(quad * 4 + r) * 40 + st * 16 + l16] = f2bf_trunc(p);
      }
    bf16x8 pf = *(const bf16x8*)(myP + l16 * 40 + quad * 8);
#pragma unroll
    for (int nt = 0; nt < 4; ++nt) {
      int dim = nt * 16 + l16;
      bf16x8 vf = *(const bf16x8*)(sV + dim * 32 + ((quad ^ ((dim >> 1) & 3)) * 8));
      accO[nt] = __builtin_amdgcn_mfma_f32_16x16x32_bf16(pf, vf, accO[nt], 0, 0, 0);
    }
    __syncthreads();
  }

#pragma unroll
  for (int r = 0; r < 4; ++r) {
    float s = l_lane[r];
    s += __shfl_xor(s, 1);
    s += __shfl_xor(s, 2);
    s += __shfl_xor(s, 4);
    s += __shfl_xor(s, 8);
    l_lane[r] = s;
  }
  float* Op = chunk ? O1 : O0;
#pragma unroll
  for (int nt = 0; nt < 4; ++nt)
#pragma unroll
    for (int r = 0; r < 4; ++r) {
      int row = q0 + quad * 4 + r;
      Op[((size_t)h * S + row) * 64 + nt * 16 + l16] = accO[nt][r];
    }
  if (l16 == 0)
#pragma unroll
    for (int r = 0; r < 4; ++r)
      lp[((size_t)h * 2 + chunk) * S + q0 + quad * 4 + r] = l_lane[r];
}

// ---------------- combine split-K partials -> ctx (bf16) ----------------
__global__ __launch_bounds__(256) void attn_combine(const float* __restrict__ O0,
                                                    const float* __restrict__ O1,
                                                    const float* __restrict__ lp,
                                                    u16* __restrict__ ctx) {
  const int S = 4096;
  int i = (blockIdx.x * 256 + threadIdx.x);
  int row = i >> 7;
  int col4 = (i & 127) * 4;
  int h = col4 >> 6, c = col4 & 63;
  size_t ob = ((size_t)h * S + row) * 64 + c;
  f32x4 o = *(const f32x4*)(O0 + ob) + *(const f32x4*)(O1 + ob);
  float l = lp[((size_t)h * 2 + 0) * S + row] + lp[((size_t)h * 2 + 1) * S + row];
  float rl = 1.f / l;
  u16x4 out;
#pragma unroll
  for (int j = 0; j < 4; ++j) out[j] = f2bf(o[j] * rl);
  *(u16x4*)(ctx + (size_t)row * 512 + col4) = out;
}

// ---------------- residual + layernorm (rows of 512) ----------------
__global__ __launch_bounds__(256) void resid_ln(const float* __restrict__ X,
                                                const float* __restrict__ Y,
                                                const float* __restrict__ g,
                                                const float* __restrict__ b,
                                                float* __restrict__ outF,
                                                u16* __restrict__ outH) {
  int row = blockIdx.x * 4 + (int)(threadIdx.x >> 6);
  int lane = threadIdx.x & 63;
  const float* x0 = X + (size_t)row * 512;
  const float* y0 = Y + (size_t)row * 512;
  int c0 = lane * 4, c1 = 256 + lane * 4;
  f32x4 v0 = *(const f32x4*)(x0 + c0) + *(const f32x4*)(y0 + c0);
  f32x4 v1 = *(const f32x4*)(x0 + c1) + *(const f32x4*)(y0 + c1);
  float s = 0.f, s2 = 0.f;
#pragma unroll
  for (int j = 0; j < 4; ++j) {
    s += v0[j] + v1[j];
    s2 += v0[j] * v0[j] + v1[j] * v1[j];
  }
#pragma unroll
  for (int m = 1; m < 64; m <<= 1) {
    s += __shfl_xor(s, m);
    s2 += __shfl_xor(s2, m);
  }
  float mean = s * (1.f / 512.f);
  float var = s2 * (1.f / 512.f) - mean * mean;
  float rs = rsqrtf(var + 1e-5f);
  f32x4 o0, o1;
#pragma unroll
  for (int j = 0; j < 4; ++j) {
    o0[j] = (v0[j] - mean) * rs * g[c0 + j] + b[c0 + j];
    o1[j] = (v1[j] - mean) * rs * g[c1 + j] + b[c1 + j];
  }
  if (outF) {
    *(f32x4*)(outF + (size_t)row * 512 + c0) = o0;
    *(f32x4*)(outF + (size_t)row * 512 + c1) = o1;
  }
  if (outH) {
    u16x4 h0, h1;
#pragma unroll
    for (int j = 0; j < 4; ++j) { h0[j] = f2bf(o0[j]); h1[j] = f2bf(o1[j]); }
    *(u16x4*)(outH + (size_t)row * 512 + c0) = h0;
    *(u16x4*)(outH + (size_t)row * 512 + c1) = h1;
  }
}

extern "C" void kernel_launch(void* const* d_in, const int* in_sizes, int n_in,
                              void* d_out, int out_size, void* d_ws, size_t ws_size,
                              hipStream_t stream) {
  (void)in_sizes; (void)n_in; (void)out_size; (void)ws_size;
  const float* x   = (const float*)d_in[0];
  const int*   mask= (const int*)d_in[1];
  const float* wq  = (const float*)d_in[2];
  const float* bq  = (const float*)d_in[3];
  const float* wk  = (const float*)d_in[4];
  const float* bk  = (const float*)d_in[5];
  const float* wv  = (const float*)d_in[6];
  const float* bv  = (const float*)d_in[7];
  const float* wo  = (const float*)d_in[8];
  const float* bo  = (const float*)d_in[9];
  const float* w1  = (const float*)d_in[10];
  const float* b1  = (const float*)d_in[11];
  const float* w2  = (const float*)d_in[12];
  const float* b2  = (const float*)d_in[13];
  const float* g1  = (const float*)d_in[14];
  const float* be1 = (const float*)d_in[15];
  const float* g2  = (const float*)d_in[16];
  const float* be2 = (const float*)d_in[17];

  const int S = 4096, D = 512, F = 2048;
  char* ws = (char*)d_ws;
  size_t cur = 0;
  auto alloc = [&](size_t bytes) {
    char* p = ws + cur;
    cur += (bytes + 255) & ~(size_t)255;
    return p;
  };
  // persistent weight region (bf16, transposed to N x K)
  u16* wqT_h = (u16*)alloc((size_t)D * D * 2); u16* wqT_l = (u16*)alloc((size_t)D * D * 2);
  u16* wkT_h = (u16*)alloc((size_t)D * D * 2); u16* wkT_l = (u16*)alloc((size_t)D * D * 2);
  u16* wvT_h = (u16*)alloc((size_t)D * D * 2); u16* wvT_l = (u16*)alloc((size_t)D * D * 2);
  u16* woT_h = (u16*)alloc((size_t)D * D * 2); u16* woT_l = (u16*)alloc((size_t)D * D * 2);
  u16* w1T_h = (u16*)alloc((size_t)D * F * 2); u16* w1T_l = (u16*)alloc((size_t)D * F * 2);
  u16* w2T_h = (u16*)alloc((size_t)D * F * 2); u16* w2T_l = (u16*)alloc((size_t)D * F * 2);
  u32* mbits = (u32*)alloc((size_t)S * S / 8);
  u16* xh = (u16*)alloc((size_t)S * D * 2);
  u16* xl = (u16*)alloc((size_t)S * D * 2);
  u16* Qh = (u16*)alloc((size_t)S * D * 2);
  u16* Ql = (u16*)alloc((size_t)S * D * 2);
  u16* Kh = (u16*)alloc((size_t)S * D * 2);
  u16* Kl = (u16*)alloc((size_t)S * D * 2);
  u16* Vt = (u16*)alloc((size_t)S * D * 2);
  u16* ctx = (u16*)alloc((size_t)S * D * 2);
  float* x1 = (float*)alloc((size_t)S * D * 4);
  u16* x1h = (u16*)alloc((size_t)S * D * 2);
  float* Qf = (float*)alloc((size_t)3 * S * D * 4);   // Qf,Kf,Vf contiguous (24MB)
  float* Kf = Qf + (size_t)S * D;
  float* Vf = Kf + (size_t)S * D;
  // aliased regions (lifetimes disjoint by stream order):
  float* proj = (float*)xh;   // 8 MB over xh+xl; zeroed AFTER combine read O0
  u16* hbuf = Qh;             // 16 MB over Qh..Kl; written by FF1 after attention
  float* ff2 = (float*)Vt;    // 4+4 MB over Vt+ctx? NO -- ctx live. Use Qf region:
  ff2 = Qf;                   // 8 MB over Qf (dead after pack_qk/vtrans); zeroed after attn
  float* O0 = (float*)xh;     // 8 MB partials chunk 0 (xh+xl dead after QKV gemm)
  float* O1 = x1;             // 8 MB partials chunk 1 (x1 written later by resid_ln)
  float* lp = (float*)x1h;    // 256 KB (x1h written later by resid_ln)

  GemmIO ioQ = {wqT_h, wqT_l, bq, Qf, nullptr, nullptr};
  GemmIO ioK = {wkT_h, wkT_l, bk, Kf, nullptr, nullptr};
  GemmIO ioV = {wvT_h, wvT_l, bv, Vf, nullptr, nullptr};
  GemmIO ioP = {woT_h, nullptr, bo, proj, nullptr, nullptr};
  GemmIO io1 = {w1T_h, nullptr, b1, nullptr, hbuf, nullptr};
  GemmIO io2 = {w2T_h, nullptr, b2, ff2, nullptr, nullptr};

  W4 wAll = {{wq, wk, wv, wo},
             {wqT_h, wkT_h, wvT_h, woT_h},
             {wqT_l, wkT_l, wvT_l, woT_l}};
  W4 wF1 = {{w1, nullptr, nullptr, nullptr}, {w1T_h, nullptr, nullptr, nullptr},
            {w1T_l, nullptr, nullptr, nullptr}};
  W4 wF2 = {{w2, nullptr, nullptr, nullptr}, {w2T_h, nullptr, nullptr, nullptr},
            {w2T_l, nullptr, nullptr, nullptr}};

  dim3 tb(32, 8);
  // 0. zero QKV fp32 accumulators (24MB)
  hipMemsetAsync(Qf, 0, (size_t)3 * S * D * 4, stream);
  // 1. converts
  convert_split<<<(S * D) / 1024, 256, 0, stream>>>(x, xh, xl);
  pack_mask<<<(S * S) / 256, 256, 0, stream>>>(mask, (unsigned long long*)mbits);
  wtrans<4><<<dim3(16, 16, 4), tb, 0, stream>>>(wAll, D, D);
  wtrans<1><<<dim3(64, 16), tb, 0, stream>>>(wF1, D, F);
  wtrans<1><<<dim3(16, 64), tb, 0, stream>>>(wF2, F, D);
  // 2. QKV projections: split (3x MFMA) for accurate logits, split-K x2, atomic fp32
  gemm_bt<1, 0, 2><<<dim3(4, 32, 6), 256, 0, stream>>>(xh, xl, ioQ, ioK, ioV, S, D, D);
  // 3. pack Q,K -> bf16 hi/lo; V -> Vt (Dh-major bf16) fused transpose
  pack_qk<<<(S * D) / 1024, 256, 0, stream>>>(Qf, Kf, Qh, Ql, Kh, Kl);
  transpose_f32_bf16<<<dim3(16, 128), tb, 0, stream>>>(Vf, Vt, S, D);
  // 4. flash attention (split-K over 2 key chunks, LDS-staged) + combine
  attn<<<dim3(16, 64), 256, 0, stream>>>(Qh, Ql, Kh, Kl, Vt, mbits, O0, O1, lp);
  attn_combine<<<(S * D / 4) / 256, 256, 0, stream>>>(O0, O1, lp, ctx);
  // 5. zero atomic accumulators for OP and FF2 (after their regions' last readers)
  hipMemsetAsync(proj, 0, (size_t)S * D * 4, stream);   // after combine read O0 (alias)
  hipMemsetAsync(ff2, 0, (size_t)S * D * 4, stream);    // after pack/vtrans read Qf (alias)
  // 6. output projection (split-K x4, atomic)
  gemm_bt<0, 0, 4><<<dim3(4, 32, 4), 256, 0, stream>>>(ctx, nullptr, ioP, ioP, ioP, S, D, D);
  // 7. residual + LN1
  resid_ln<<<S / 4, 256, 0, stream>>>(x, proj, g1, be1, x1, x1h);
  // 8. FFN: FF1 direct (512 blocks), FF2 split-K x4 atomic
  gemm_bt<0, 1, 1><<<dim3(16, 32, 1), 256, 0, stream>>>(x1h, nullptr, io1, io1, io1, S, F, D);
  gemm_bt<0, 0, 4><<<dim3(4, 32, 4), 256, 0, stream>>>(hbuf, nullptr, io2, io2, io2, S, D, F);
  // 9. residual + LN2 -> final fp32 output
  resid_ln<<<S / 4, 256, 0, stream>>>(x1, ff2, g2, be2, (float*)d_out, nullptr);
}

// Round 5
// 397.622 us; speedup vs baseline: 2.0396x; 1.1612x over previous
//
#include <hip/hip_runtime.h>

typedef unsigned short u16;
typedef unsigned int u32;
typedef unsigned long long u64;
typedef __attribute__((ext_vector_type(4))) float f32x4;
typedef __attribute__((ext_vector_type(8))) short bf16x8;   // 8 bf16 (4 VGPRs)
typedef __attribute__((ext_vector_type(4))) u16 u16x4;

#define DEV __device__ __forceinline__

DEV u16 f2bf(float f) {               // RNE fp32 -> bf16
  union { float f; u32 u; } c; c.f = f;
  u32 u = c.u;
  u += 0x7fffu + ((u >> 16) & 1u);
  return (u16)(u >> 16);
}
DEV float bf2f(u16 h) {
  union { u32 u; float f; } c; c.u = ((u32)h) << 16;
  return c.f;
}
DEV u16 f2bf_trunc(float f) {         // truncating pack (p>=0; softmax normalizes the bias)
  union { float f; u32 u; } c; c.f = f;
  return (u16)(c.u >> 16);
}

// async global->LDS, 16B per lane. Dest is WAVE-UNIFORM base + lane*16 (m104/m108).
DEV void gload_lds16(const void* g, void* l) {
  __builtin_amdgcn_global_load_lds(
      (const __attribute__((address_space(1))) u32*)(u64)g,
      (__attribute__((address_space(3))) u32*)(u32)(u64)l,   // low 32 bits = LDS offset
      16, 0, 0);
}

// ---------------- fused prep: x split + 6 weight transposes + mask pack ----------------
// One dispatch replaces 6 (launch overhead ~10us each dominates small kernels).
// Block ranges: [0,2048) convert_split; [2048,5120) wtrans; [5120,70656) pack_mask.
struct PrepW { const float* w; u16* th; u16* tl; int R, C, gxmask, gxshift; };
struct PrepArgs {
  const float* x; u16* xh; u16* xl;
  const int* mask; unsigned long long* mbits;
  PrepW pw[6];
};

__global__ __launch_bounds__(256) void prep(PrepArgs a) {
  __shared__ float t[32][33];
  int b = blockIdx.x, tid = threadIdx.x;
  if (b < 2048) {                       // x -> bf16 hi/lo
    int i = (b * 256 + tid) * 4;
    f32x4 v = *(const f32x4*)(a.x + i);
    u16x4 h, l;
#pragma unroll
    for (int j = 0; j < 4; ++j) { h[j] = f2bf(v[j]); l[j] = f2bf(v[j] - bf2f(h[j])); }
    *(u16x4*)(a.xh + i) = h;
    *(u16x4*)(a.xl + i) = l;
    return;
  }
  b -= 2048;
  if (b < 3072) {                       // weight (R,C) -> transposed hi/lo (C,R)
    int wi, base;
    if (b < 1024) { wi = b >> 8; base = b & 255; }
    else if (b < 2048) { wi = 4; base = b - 1024; }
    else { wi = 5; base = b - 2048; }
    PrepW p = a.pw[wi];
    int c0 = (base & p.gxmask) * 32, r0 = (base >> p.gxshift) * 32;
    int tx = tid & 31, ty = tid >> 5;
#pragma unroll
    for (int i = 0; i < 4; ++i)
      t[ty + 8 * i][tx] = p.w[(size_t)(r0 + ty + 8 * i) * p.C + c0 + tx];
    __syncthreads();
#pragma unroll
    for (int i = 0; i < 4; ++i) {
      float v = t[tx][ty + 8 * i];
      u16 h = f2bf(v);
      size_t o = (size_t)(c0 + ty + 8 * i) * p.R + r0 + tx;
      p.th[o] = h;
      p.tl[o] = f2bf(v - bf2f(h));
    }
    return;
  }
  b -= 3072;                            // mask -> bitmask
  size_t i = (size_t)b * 256 + tid;
  unsigned long long bb = __ballot(a.mask[i] != 0);
  if ((tid & 63) == 0) a.mbits[i >> 6] = bb;
}

// ---------------- QKV GEMM: staged, hi/lo split (3 MFMA), direct bf16 epilogue ----------
// z=0 -> Qh/Ql, z=1 -> Kh/Kl, z=2 -> Vt (transposed bf16, Dh-major).
struct QkvArgs {
  const u16 *Ah, *Al;
  const u16 *Bh[3], *Bl[3];
  const float* bias[3];
  u16 *Qh, *Ql, *Kh, *Kl, *Vt;
};

__global__ __launch_bounds__(256) void gemm_qkv(QkvArgs a) {
  const int K = 512;
  const int z = blockIdx.z;
  const u16* __restrict__ Bh = a.Bh[z];
  const u16* __restrict__ Bl = a.Bl[z];
  const float* __restrict__ bias = a.bias[z];
  const int bn = blockIdx.x * 128, bm = blockIdx.y * 128;
  const int tid = threadIdx.x;
  const int wave = tid >> 6, lane = tid & 63;
  const int l16 = lane & 15, quad = lane >> 4;
  const int wm = (wave >> 1) * 64, wn = (wave & 1) * 64;

  __shared__ u16 sA[128 * 32];
  __shared__ u16 sB[128 * 32];
  __shared__ u16 sAl[128 * 32];
  __shared__ u16 sBl[128 * 32];

  const int srow = wave * 32 + (lane >> 2);
  const int scol = (lane & 3) * 8;
  const u16* srcA0 = a.Ah + (size_t)(bm + srow) * K + scol;
  const u16* srcB0 = Bh + (size_t)(bn + srow) * K + scol;
  const u16* srcAl0 = a.Al + (size_t)(bm + srow) * K + scol;
  const u16* srcBl0 = Bl + (size_t)(bn + srow) * K + scol;
  const size_t half_off = (size_t)16 * K;
  u16* dstA = sA + wave * 1024;
  u16* dstB = sB + wave * 1024;
  u16* dstAl = sAl + wave * 1024;
  u16* dstBl = sBl + wave * 1024;

  f32x4 acc[4][4] = {};

  for (int kt = 0; kt < K; kt += 32) {
    gload_lds16(srcA0 + kt, dstA);
    gload_lds16(srcA0 + half_off + kt, dstA + 512);
    gload_lds16(srcB0 + kt, dstB);
    gload_lds16(srcB0 + half_off + kt, dstB + 512);
    gload_lds16(srcAl0 + kt, dstAl);
    gload_lds16(srcAl0 + half_off + kt, dstAl + 512);
    gload_lds16(srcBl0 + kt, dstBl);
    gload_lds16(srcBl0 + half_off + kt, dstBl + 512);
    __syncthreads();

    bf16x8 a_h[4], b_h[4], a_l[4], b_l[4];
#pragma unroll
    for (int mt = 0; mt < 4; ++mt) {
      a_h[mt] = *(const bf16x8*)(sA + (wm + mt * 16 + l16) * 32 + quad * 8);
      a_l[mt] = *(const bf16x8*)(sAl + (wm + mt * 16 + l16) * 32 + quad * 8);
    }
#pragma unroll
    for (int nt = 0; nt < 4; ++nt) {
      b_h[nt] = *(const bf16x8*)(sB + (wn + nt * 16 + l16) * 32 + quad * 8);
      b_l[nt] = *(const bf16x8*)(sBl + (wn + nt * 16 + l16) * 32 + quad * 8);
    }
#pragma unroll
    for (int mt = 0; mt < 4; ++mt)
#pragma unroll
      for (int nt = 0; nt < 4; ++nt) {
        acc[mt][nt] = __builtin_amdgcn_mfma_f32_16x16x32_bf16(a_h[mt], b_h[nt], acc[mt][nt], 0, 0, 0);
        acc[mt][nt] = __builtin_amdgcn_mfma_f32_16x16x32_bf16(a_h[mt], b_l[nt], acc[mt][nt], 0, 0, 0);
        acc[mt][nt] = __builtin_amdgcn_mfma_f32_16x16x32_bf16(a_l[mt], b_h[nt], acc[mt][nt], 0, 0, 0);
      }
    __syncthreads();
  }

  if (z == 2) {
    // V: write transposed bf16 Vt[dim][seq]; rows (r) are register-contiguous -> 8B stores
#pragma unroll
    for (int nt = 0; nt < 4; ++nt) {
      int col = bn + wn + nt * 16 + l16;
      float bv = bias[col];
#pragma unroll
      for (int mt = 0; mt < 4; ++mt) {
        int row0 = bm + wm + mt * 16 + quad * 4;
        u16x4 o;
#pragma unroll
        for (int r = 0; r < 4; ++r) o[r] = f2bf(acc[mt][nt][r] + bv);
        *(u16x4*)(a.Vt + (size_t)col * 4096 + row0) = o;
      }
    }
  } else {
    u16* __restrict__ Ch = (z == 0) ? a.Qh : a.Kh;
    u16* __restrict__ Cl = (z == 0) ? a.Ql : a.Kl;
#pragma unroll
    for (int mt = 0; mt < 4; ++mt)
#pragma unroll
      for (int nt = 0; nt < 4; ++nt) {
        int col = bn + wn + nt * 16 + l16;
        float bv = bias[col];
#pragma unroll
        for (int r = 0; r < 4; ++r) {
          int row = bm + wm + mt * 16 + quad * 4 + r;
          float v = acc[mt][nt][r] + bv;
          u16 h = f2bf(v);
          size_t oidx = (size_t)row * 512 + col;
          Ch[oidx] = h;
          Cl[oidx] = f2bf(v - bf2f(h));
        }
      }
  }
}

// ---------------- generic staged GEMM: C[M,N] = A[M,K] @ B^T[N,K] + bias ----------------
template <int RELU, int BF16OUT>
__global__ __launch_bounds__(256) void gemm_bt(const u16* __restrict__ Ah,
                                               const u16* __restrict__ Bh,
                                               const float* __restrict__ bias,
                                               float* __restrict__ Cf,
                                               u16* __restrict__ Ch,
                                               int N, int K) {
  const int bn = blockIdx.x * 128, bm = blockIdx.y * 128;
  const int tid = threadIdx.x;
  const int wave = tid >> 6, lane = tid & 63;
  const int l16 = lane & 15, quad = lane >> 4;
  const int wm = (wave >> 1) * 64, wn = (wave & 1) * 64;

  __shared__ u16 sA[128 * 32];
  __shared__ u16 sB[128 * 32];

  const int srow = wave * 32 + (lane >> 2);
  const int scol = (lane & 3) * 8;
  const u16* srcA0 = Ah + (size_t)(bm + srow) * K + scol;
  const u16* srcB0 = Bh + (size_t)(bn + srow) * K + scol;
  const size_t half_off = (size_t)16 * K;
  u16* dstA = sA + wave * 1024;
  u16* dstB = sB + wave * 1024;

  f32x4 acc[4][4] = {};

  for (int kt = 0; kt < K; kt += 32) {
    gload_lds16(srcA0 + kt, dstA);
    gload_lds16(srcA0 + half_off + kt, dstA + 512);
    gload_lds16(srcB0 + kt, dstB);
    gload_lds16(srcB0 + half_off + kt, dstB + 512);
    __syncthreads();

    bf16x8 a_h[4], b_h[4];
#pragma unroll
    for (int mt = 0; mt < 4; ++mt)
      a_h[mt] = *(const bf16x8*)(sA + (wm + mt * 16 + l16) * 32 + quad * 8);
#pragma unroll
    for (int nt = 0; nt < 4; ++nt)
      b_h[nt] = *(const bf16x8*)(sB + (wn + nt * 16 + l16) * 32 + quad * 8);
#pragma unroll
    for (int mt = 0; mt < 4; ++mt)
#pragma unroll
      for (int nt = 0; nt < 4; ++nt)
        acc[mt][nt] = __builtin_amdgcn_mfma_f32_16x16x32_bf16(a_h[mt], b_h[nt], acc[mt][nt], 0, 0, 0);
    __syncthreads();
  }

#pragma unroll
  for (int mt = 0; mt < 4; ++mt)
#pragma unroll
    for (int nt = 0; nt < 4; ++nt) {
      int col = bn + wn + nt * 16 + l16;
      float bv = bias ? bias[col] : 0.f;
#pragma unroll
      for (int r = 0; r < 4; ++r) {
        int row = bm + wm + mt * 16 + quad * 4 + r;
        float v = acc[mt][nt][r] + bv;
        if (RELU) v = fmaxf(v, 0.f);
        size_t oidx = (size_t)row * N + col;
        if (BF16OUT) Ch[oidx] = f2bf(v);
        else Cf[oidx] = v;
      }
    }
}

// ---------------- flash attention, split-K x4, LDS-staged K/V ----------------
// Grid (32 head*chunk, 64 qblocks) = 2048 blocks -> 8 blocks/CU (100% theor.
// occupancy; r4 was VALU-bound at 58% busy / 36% occupancy). kchunk=1024.
__global__ __launch_bounds__(256) void attn(const u16* __restrict__ Qh, const u16* __restrict__ Ql,
                                            const u16* __restrict__ Kh, const u16* __restrict__ Kl,
                                            const u16* __restrict__ Vt, const u32* __restrict__ mb,
                                            float* __restrict__ O0, float* __restrict__ O1,
                                            float* __restrict__ O2, float* __restrict__ O3,
                                            float* __restrict__ lp) {
  const int S = 4096, D = 512;
  const float L2E = 1.44269504088896340736f;
  const int h = blockIdx.x >> 2, chunk = blockIdx.x & 3;
  const int tid = threadIdx.x, wave = tid >> 6, lane = tid & 63;
  const int l16 = lane & 15, quad = lane >> 4;
  const int q0 = blockIdx.y * 64 + wave * 16;
  const int kbeg = chunk * 1024;

  __shared__ u16 lds[6144 + 4 * 640];
  u16* sKh = lds;
  u16* sKl = lds + 2048;
  u16* sV  = lds + 4096;
  u16* myP = lds + 6144 + wave * 640;

  const int skey = wave * 8 + (lane >> 3);
  const int kc   = lane & 7;
  const u16* srcKh = Kh + (size_t)(kbeg + skey) * D + h * 64 + ((kc ^ (skey & 7)) * 8);
  const u16* srcKl = Kl + (size_t)(kbeg + skey) * D + h * 64 + ((kc ^ (skey & 7)) * 8);
  const int sdim = wave * 16 + (lane >> 2);
  const int vc   = lane & 3;
  const u16* srcV = Vt + (size_t)(h * 64 + sdim) * S + kbeg + ((vc ^ ((sdim >> 1) & 3)) * 8);
  u16* dstKh = sKh + wave * 512;
  u16* dstKl = sKl + wave * 512;
  u16* dstV  = sV  + wave * 512;

  bf16x8 qh[2], ql[2];
  {
    size_t qb = (size_t)(q0 + l16) * D + h * 64 + quad * 8;
    qh[0] = *(const bf16x8*)(Qh + qb); qh[1] = *(const bf16x8*)(Qh + qb + 32);
    ql[0] = *(const bf16x8*)(Ql + qb); ql[1] = *(const bf16x8*)(Ql + qb + 32);
  }

  float l_lane[4] = {0.f, 0.f, 0.f, 0.f};
  f32x4 accO[4] = {};

  const int ks = l16 & 7;
  const int c0 = (quad ^ ks) * 8;
  const int c1 = ((quad ^ 4) ^ ks) * 8;

  for (int it = 0; it < 32; ++it) {
    gload_lds16(srcKh, dstKh);
    gload_lds16(srcKl, dstKl);
    gload_lds16(srcV, dstV);
    srcKh += 32 * D; srcKl += 32 * D; srcV += 32;
    __syncthreads();

    const int km = (kbeg >> 5) + it;
    u32 words[4];
#pragma unroll
    for (int r = 0; r < 4; ++r)
      words[r] = mb[(size_t)(q0 + quad * 4 + r) * 128 + km];

    f32x4 sc[2] = {};
#pragma unroll
    for (int st = 0; st < 2; ++st) {
      const u16* rowh = sKh + (st * 16 + l16) * 64;
      const u16* rowl = sKl + (st * 16 + l16) * 64;
      bf16x8 kh0 = *(const bf16x8*)(rowh + c0);
      bf16x8 kh1 = *(const bf16x8*)(rowh + c1);
      bf16x8 kl0 = *(const bf16x8*)(rowl + c0);
      bf16x8 kl1 = *(const bf16x8*)(rowl + c1);
      sc[st] = __builtin_amdgcn_mfma_f32_16x16x32_bf16(qh[0], kh0, sc[st], 0, 0, 0);
      sc[st] = __builtin_amdgcn_mfma_f32_16x16x32_bf16(qh[1], kh1, sc[st], 0, 0, 0);
      sc[st] = __builtin_amdgcn_mfma_f32_16x16x32_bf16(qh[0], kl0, sc[st], 0, 0, 0);
      sc[st] = __builtin_amdgcn_mfma_f32_16x16x32_bf16(qh[1], kl1, sc[st], 0, 0, 0);
      sc[st] = __builtin_amdgcn_mfma_f32_16x16x32_bf16(ql[0], kh0, sc[st], 0, 0, 0);
      sc[st] = __builtin_amdgcn_mfma_f32_16x16x32_bf16(ql[1], kh1, sc[st], 0, 0, 0);
    }
#pragma unroll
    for (int st = 0; st < 2; ++st)
#pragma unroll
      for (int r = 0; r < 4; ++r) {
        bool keep = (words[r] >> (st * 16 + l16)) & 1u;
        float p = keep ? exp2f(sc[st][r] * L2E) : 0.f;
        l_lane[r] += p;
        myP[(quad * 4 + r) * 40 + st * 16 + l16] = f2bf_trunc(p);
      }
    bf16x8 pf = *(const bf16x8*)(myP + l16 * 40 + quad * 8);
#pragma unroll
    for (int nt = 0; nt < 4; ++nt) {
      int dim = nt * 16 + l16;
      bf16x8 vf = *(const bf16x8*)(sV + dim * 32 + ((quad ^ ((dim >> 1) & 3)) * 8));
      accO[nt] = __builtin_amdgcn_mfma_f32_16x16x32_bf16(pf, vf, accO[nt], 0, 0, 0);
    }
    __syncthreads();
  }

#pragma unroll
  for (int r = 0; r < 4; ++r) {
    float s = l_lane[r];
    s += __shfl_xor(s, 1);
    s += __shfl_xor(s, 2);
    s += __shfl_xor(s, 4);
    s += __shfl_xor(s, 8);
    l_lane[r] = s;
  }
  float* Op = (chunk < 2) ? (chunk ? O1 : O0) : (chunk == 2 ? O2 : O3);
#pragma unroll
  for (int nt = 0; nt < 4; ++nt)
#pragma unroll
    for (int r = 0; r < 4; ++r) {
      int row = q0 + quad * 4 + r;
      Op[((size_t)h * S + row) * 64 + nt * 16 + l16] = accO[nt][r];
    }
  if (l16 == 0)
#pragma unroll
    for (int r = 0; r < 4; ++r)
      lp[((size_t)h * 4 + chunk) * S + q0 + quad * 4 + r] = l_lane[r];
}

// ---------------- combine split-K partials -> ctx (bf16) ----------------
__global__ __launch_bounds__(256) void attn_combine(const float* __restrict__ O0,
                                                    const float* __restrict__ O1,
                                                    const float* __restrict__ O2,
                                                    const float* __restrict__ O3,
                                                    const float* __restrict__ lp,
                                                    u16* __restrict__ ctx) {
  const int S = 4096;
  int i = (blockIdx.x * 256 + threadIdx.x);
  int row = i >> 7;
  int col4 = (i & 127) * 4;
  int h = col4 >> 6, c = col4 & 63;
  size_t ob = ((size_t)h * S + row) * 64 + c;
  f32x4 o = *(const f32x4*)(O0 + ob) + *(const f32x4*)(O1 + ob) +
            *(const f32x4*)(O2 + ob) + *(const f32x4*)(O3 + ob);
  float l = lp[((size_t)h * 4 + 0) * S + row] + lp[((size_t)h * 4 + 1) * S + row] +
            lp[((size_t)h * 4 + 2) * S + row] + lp[((size_t)h * 4 + 3) * S + row];
  float rl = 1.f / l;
  u16x4 out;
#pragma unroll
  for (int j = 0; j < 4; ++j) out[j] = f2bf(o[j] * rl);
  *(u16x4*)(ctx + (size_t)row * 512 + col4) = out;
}

// ---------------- residual + layernorm (rows of 512) ----------------
__global__ __launch_bounds__(256) void resid_ln(const float* __restrict__ X,
                                                const float* __restrict__ Y,
                                                const float* __restrict__ g,
                                                const float* __restrict__ b,
                                                float* __restrict__ outF,
                                                u16* __restrict__ outH) {
  int row = blockIdx.x * 4 + (int)(threadIdx.x >> 6);
  int lane = threadIdx.x & 63;
  const float* x0 = X + (size_t)row * 512;
  const float* y0 = Y + (size_t)row * 512;
  int c0 = lane * 4, c1 = 256 + lane * 4;
  f32x4 v0 = *(const f32x4*)(x0 + c0) + *(const f32x4*)(y0 + c0);
  f32x4 v1 = *(const f32x4*)(x0 + c1) + *(const f32x4*)(y0 + c1);
  float s = 0.f, s2 = 0.f;
#pragma unroll
  for (int j = 0; j < 4; ++j) {
    s += v0[j] + v1[j];
    s2 += v0[j] * v0[j] + v1[j] * v1[j];
  }
#pragma unroll
  for (int m = 1; m < 64; m <<= 1) {
    s += __shfl_xor(s, m);
    s2 += __shfl_xor(s2, m);
  }
  float mean = s * (1.f / 512.f);
  float var = s2 * (1.f / 512.f) - mean * mean;
  float rs = rsqrtf(var + 1e-5f);
  f32x4 o0, o1;
#pragma unroll
  for (int j = 0; j < 4; ++j) {
    o0[j] = (v0[j] - mean) * rs * g[c0 + j] + b[c0 + j];
    o1[j] = (v1[j] - mean) * rs * g[c1 + j] + b[c1 + j];
  }
  if (outF) {
    *(f32x4*)(outF + (size_t)row * 512 + c0) = o0;
    *(f32x4*)(outF + (size_t)row * 512 + c1) = o1;
  }
  if (outH) {
    u16x4 h0, h1;
#pragma unroll
    for (int j = 0; j < 4; ++j) { h0[j] = f2bf(o0[j]); h1[j] = f2bf(o1[j]); }
    *(u16x4*)(outH + (size_t)row * 512 + c0) = h0;
    *(u16x4*)(outH + (size_t)row * 512 + c1) = h1;
  }
}

extern "C" void kernel_launch(void* const* d_in, const int* in_sizes, int n_in,
                              void* d_out, int out_size, void* d_ws, size_t ws_size,
                              hipStream_t stream) {
  (void)in_sizes; (void)n_in; (void)out_size; (void)ws_size;
  const float* x   = (const float*)d_in[0];
  const int*   mask= (const int*)d_in[1];
  const float* wq  = (const float*)d_in[2];
  const float* bq  = (const float*)d_in[3];
  const float* wk  = (const float*)d_in[4];
  const float* bk  = (const float*)d_in[5];
  const float* wv  = (const float*)d_in[6];
  const float* bv  = (const float*)d_in[7];
  const float* wo  = (const float*)d_in[8];
  const float* bo  = (const float*)d_in[9];
  const float* w1  = (const float*)d_in[10];
  const float* b1  = (const float*)d_in[11];
  const float* w2  = (const float*)d_in[12];
  const float* b2  = (const float*)d_in[13];
  const float* g1  = (const float*)d_in[14];
  const float* be1 = (const float*)d_in[15];
  const float* g2  = (const float*)d_in[16];
  const float* be2 = (const float*)d_in[17];

  const int S = 4096, D = 512, F = 2048;
  char* ws = (char*)d_ws;
  size_t cur = 0;
  auto alloc = [&](size_t bytes) {
    char* p = ws + cur;
    cur += (bytes + 255) & ~(size_t)255;
    return p;
  };
  u16* wqT_h = (u16*)alloc((size_t)D * D * 2); u16* wqT_l = (u16*)alloc((size_t)D * D * 2);
  u16* wkT_h = (u16*)alloc((size_t)D * D * 2); u16* wkT_l = (u16*)alloc((size_t)D * D * 2);
  u16* wvT_h = (u16*)alloc((size_t)D * D * 2); u16* wvT_l = (u16*)alloc((size_t)D * D * 2);
  u16* woT_h = (u16*)alloc((size_t)D * D * 2); u16* woT_l = (u16*)alloc((size_t)D * D * 2);
  u16* w1T_h = (u16*)alloc((size_t)D * F * 2); u16* w1T_l = (u16*)alloc((size_t)D * F * 2);
  u16* w2T_h = (u16*)alloc((size_t)D * F * 2); u16* w2T_l = (u16*)alloc((size_t)D * F * 2);
  u32* mbits = (u32*)alloc((size_t)S * S / 8);
  u16* xh = (u16*)alloc((size_t)S * D * 2);
  u16* xl = (u16*)alloc((size_t)S * D * 2);
  u16* Qh = (u16*)alloc((size_t)S * D * 2);
  u16* Ql = (u16*)alloc((size_t)S * D * 2);
  u16* Kh = (u16*)alloc((size_t)S * D * 2);
  u16* Kl = (u16*)alloc((size_t)S * D * 2);
  u16* Vt = (u16*)alloc((size_t)S * D * 2);
  u16* ctx = (u16*)alloc((size_t)S * D * 2);
  float* x1 = (float*)alloc((size_t)S * D * 4);
  u16* x1h = (u16*)alloc((size_t)S * D * 2);
  float* Oex = (float*)alloc((size_t)2 * S * D * 4);   // O2,O3 (16MB fresh)
  // aliased regions (lifetimes disjoint by stream order):
  float* O0 = (float*)xh;     // 8MB over xh+xl (dead after QKV gemm)
  float* O1 = x1;             // 8MB (x1 written later by resid_ln, after combine)
  float* O2 = Oex;            // 8MB fresh
  float* O3 = Oex + (size_t)S * D;  // 8MB fresh
  float* lp = (float*)x1h;    // 512KB (x1h written later by resid_ln)
  float* proj = (float*)xh;   // OP output, after combine read O0
  u16* hbuf = Qh;             // FF1 output (16MB over Qh..Kl), after attn read Q/K
  float* ff2 = Oex;           // FF2 output, after combine read O2

  PrepArgs pa;
  pa.x = x; pa.xh = xh; pa.xl = xl;
  pa.mask = mask; pa.mbits = (unsigned long long*)mbits;
  pa.pw[0] = {wq, wqT_h, wqT_l, D, D, 15, 4};
  pa.pw[1] = {wk, wkT_h, wkT_l, D, D, 15, 4};
  pa.pw[2] = {wv, wvT_h, wvT_l, D, D, 15, 4};
  pa.pw[3] = {wo, woT_h, woT_l, D, D, 15, 4};
  pa.pw[4] = {w1, w1T_h, w1T_l, D, F, 63, 6};   // grid (64,16)
  pa.pw[5] = {w2, w2T_h, w2T_l, F, D, 15, 4};   // grid (16,64)

  QkvArgs qa;
  qa.Ah = xh; qa.Al = xl;
  qa.Bh[0] = wqT_h; qa.Bh[1] = wkT_h; qa.Bh[2] = wvT_h;
  qa.Bl[0] = wqT_l; qa.Bl[1] = wkT_l; qa.Bl[2] = wvT_l;
  qa.bias[0] = bq; qa.bias[1] = bk; qa.bias[2] = bv;
  qa.Qh = Qh; qa.Ql = Ql; qa.Kh = Kh; qa.Kl = Kl; qa.Vt = Vt;

  // 1. fused prep (x split + 6 weight transposes + mask pack)
  prep<<<70656, 256, 0, stream>>>(pa);
  // 2. QKV projection: direct bf16 hi/lo epilogue + V transposed (1 dispatch)
  gemm_qkv<<<dim3(4, 32, 3), 256, 0, stream>>>(qa);
  // 3. flash attention (split-K x4) + combine
  attn<<<dim3(32, 64), 256, 0, stream>>>(Qh, Ql, Kh, Kl, Vt, mbits, O0, O1, O2, O3, lp);
  attn_combine<<<(S * D / 4) / 256, 256, 0, stream>>>(O0, O1, O2, O3, lp, ctx);
  // 4. output projection -> proj fp32
  gemm_bt<0, 0><<<dim3(4, 32), 256, 0, stream>>>(ctx, woT_h, bo, proj, nullptr, D, D);
  // 5. residual + LN1
  resid_ln<<<S / 4, 256, 0, stream>>>(x, proj, g1, be1, x1, x1h);
  // 6. FFN
  gemm_bt<1, 1><<<dim3(16, 32), 256, 0, stream>>>(x1h, w1T_h, b1, nullptr, hbuf, F, D);
  gemm_bt<0, 0><<<dim3(4, 32), 256, 0, stream>>>(hbuf, w2T_h, b2, ff2, nullptr, D, F);
  // 7. residual + LN2 -> final fp32 output
  resid_ln<<<S / 4, 256, 0, stream>>>(x1, ff2, g2, be2, (float*)d_out, nullptr);
}

// Round 6
// 370.759 us; speedup vs baseline: 2.1873x; 1.0725x over previous
//
#include <hip/hip_runtime.h>

typedef unsigned short u16;
typedef unsigned int u32;
typedef unsigned long long u64;
typedef __attribute__((ext_vector_type(4))) float f32x4;
typedef __attribute__((ext_vector_type(8))) short bf16x8;   // 8 bf16 (4 VGPRs)
typedef __attribute__((ext_vector_type(4))) u16 u16x4;
typedef __attribute__((ext_vector_type(2))) u32 u32x2;

#define DEV __device__ __forceinline__

DEV u16 f2bf(float f) {               // RNE fp32 -> bf16
  union { float f; u32 u; } c; c.f = f;
  u32 u = c.u;
  u += 0x7fffu + ((u >> 16) & 1u);
  return (u16)(u >> 16);
}
DEV float bf2f(u16 h) {
  union { u32 u; float f; } c; c.u = ((u32)h) << 16;
  return c.f;
}
DEV u32 fbits(float f) { union { float f; u32 u; } c; c.f = f; return c.u; }
// pack two fp32 -> two truncated bf16 in one u32 (a = low, b = high)
DEV u32 packtrunc(float a, float b) {
  return (fbits(b) & 0xFFFF0000u) | (fbits(a) >> 16);
}

// async global->LDS, 16B per lane. Dest is WAVE-UNIFORM base + lane*16 (m104/m108).
DEV void gload_lds16(const void* g, void* l) {
  __builtin_amdgcn_global_load_lds(
      (const __attribute__((address_space(1))) u32*)(u64)g,
      (__attribute__((address_space(3))) u32*)(u32)(u64)l,   // low 32 bits = LDS offset
      16, 0, 0);
}

// ---------------- fused prep: x split + 6 weight transposes + mask pack ----------------
struct PrepW { const float* w; u16* th; u16* tl; int R, C, gxmask, gxshift; };
struct PrepArgs {
  const float* x; u16* xh; u16* xl;
  const int* mask; unsigned long long* mbits;
  PrepW pw[6];
};

__global__ __launch_bounds__(256) void prep(PrepArgs a) {
  __shared__ float t[32][33];
  int b = blockIdx.x, tid = threadIdx.x;
  if (b < 2048) {                       // x -> bf16 hi/lo
    int i = (b * 256 + tid) * 4;
    f32x4 v = *(const f32x4*)(a.x + i);
    u16x4 h, l;
#pragma unroll
    for (int j = 0; j < 4; ++j) { h[j] = f2bf(v[j]); l[j] = f2bf(v[j] - bf2f(h[j])); }
    *(u16x4*)(a.xh + i) = h;
    *(u16x4*)(a.xl + i) = l;
    return;
  }
  b -= 2048;
  if (b < 3072) {                       // weight (R,C) -> transposed hi/lo (C,R)
    int wi, base;
    if (b < 1024) { wi = b >> 8; base = b & 255; }
    else if (b < 2048) { wi = 4; base = b - 1024; }
    else { wi = 5; base = b - 2048; }
    PrepW p = a.pw[wi];
    int c0 = (base & p.gxmask) * 32, r0 = (base >> p.gxshift) * 32;
    int tx = tid & 31, ty = tid >> 5;
#pragma unroll
    for (int i = 0; i < 4; ++i)
      t[ty + 8 * i][tx] = p.w[(size_t)(r0 + ty + 8 * i) * p.C + c0 + tx];
    __syncthreads();
#pragma unroll
    for (int i = 0; i < 4; ++i) {
      float v = t[tx][ty + 8 * i];
      u16 h = f2bf(v);
      size_t o = (size_t)(c0 + ty + 8 * i) * p.R + r0 + tx;
      p.th[o] = h;
      p.tl[o] = f2bf(v - bf2f(h));
    }
    return;
  }
  b -= 3072;                            // mask -> bitmask
  size_t i = (size_t)b * 256 + tid;
  unsigned long long bb = __ballot(a.mask[i] != 0);
  if ((tid & 63) == 0) a.mbits[i >> 6] = bb;
}

// ---------------- QKV GEMM: staged, hi/lo split (3 MFMA) ----------------
// z=0 -> Qh/Ql (prescaled by log2e), z=1 -> Kh, z=2 -> Vt (transposed bf16).
struct QkvArgs {
  const u16 *Ah, *Al;
  const u16 *Bh[3], *Bl[3];
  const float* bias[3];
  u16 *Qh, *Ql, *Kh, *Vt;
};

__global__ __launch_bounds__(256) void gemm_qkv(QkvArgs a) {
  const int K = 512;
  const float L2E = 1.44269504088896340736f;
  const int z = blockIdx.z;
  const u16* __restrict__ Bh = a.Bh[z];
  const u16* __restrict__ Bl = a.Bl[z];
  const float* __restrict__ bias = a.bias[z];
  const int bn = blockIdx.x * 128, bm = blockIdx.y * 128;
  const int tid = threadIdx.x;
  const int wave = tid >> 6, lane = tid & 63;
  const int l16 = lane & 15, quad = lane >> 4;
  const int wm = (wave >> 1) * 64, wn = (wave & 1) * 64;

  __shared__ u16 sA[128 * 32];
  __shared__ u16 sB[128 * 32];
  __shared__ u16 sAl[128 * 32];
  __shared__ u16 sBl[128 * 32];

  const int srow = wave * 32 + (lane >> 2);
  const int scol = (lane & 3) * 8;
  const u16* srcA0 = a.Ah + (size_t)(bm + srow) * K + scol;
  const u16* srcB0 = Bh + (size_t)(bn + srow) * K + scol;
  const u16* srcAl0 = a.Al + (size_t)(bm + srow) * K + scol;
  const u16* srcBl0 = Bl + (size_t)(bn + srow) * K + scol;
  const size_t half_off = (size_t)16 * K;
  u16* dstA = sA + wave * 1024;
  u16* dstB = sB + wave * 1024;
  u16* dstAl = sAl + wave * 1024;
  u16* dstBl = sBl + wave * 1024;

  f32x4 acc[4][4] = {};

  for (int kt = 0; kt < K; kt += 32) {
    gload_lds16(srcA0 + kt, dstA);
    gload_lds16(srcA0 + half_off + kt, dstA + 512);
    gload_lds16(srcB0 + kt, dstB);
    gload_lds16(srcB0 + half_off + kt, dstB + 512);
    gload_lds16(srcAl0 + kt, dstAl);
    gload_lds16(srcAl0 + half_off + kt, dstAl + 512);
    gload_lds16(srcBl0 + kt, dstBl);
    gload_lds16(srcBl0 + half_off + kt, dstBl + 512);
    __syncthreads();

    bf16x8 a_h[4], b_h[4], a_l[4], b_l[4];
#pragma unroll
    for (int mt = 0; mt < 4; ++mt) {
      a_h[mt] = *(const bf16x8*)(sA + (wm + mt * 16 + l16) * 32 + quad * 8);
      a_l[mt] = *(const bf16x8*)(sAl + (wm + mt * 16 + l16) * 32 + quad * 8);
    }
#pragma unroll
    for (int nt = 0; nt < 4; ++nt) {
      b_h[nt] = *(const bf16x8*)(sB + (wn + nt * 16 + l16) * 32 + quad * 8);
      b_l[nt] = *(const bf16x8*)(sBl + (wn + nt * 16 + l16) * 32 + quad * 8);
    }
#pragma unroll
    for (int mt = 0; mt < 4; ++mt)
#pragma unroll
      for (int nt = 0; nt < 4; ++nt) {
        acc[mt][nt] = __builtin_amdgcn_mfma_f32_16x16x32_bf16(a_h[mt], b_h[nt], acc[mt][nt], 0, 0, 0);
        acc[mt][nt] = __builtin_amdgcn_mfma_f32_16x16x32_bf16(a_h[mt], b_l[nt], acc[mt][nt], 0, 0, 0);
        acc[mt][nt] = __builtin_amdgcn_mfma_f32_16x16x32_bf16(a_l[mt], b_h[nt], acc[mt][nt], 0, 0, 0);
      }
    __syncthreads();
  }

  if (z == 2) {
    // V: write transposed bf16 Vt[dim][seq]; r-regs are seq-contiguous -> 8B stores
#pragma unroll
    for (int nt = 0; nt < 4; ++nt) {
      int col = bn + wn + nt * 16 + l16;
      float bv = bias[col];
#pragma unroll
      for (int mt = 0; mt < 4; ++mt) {
        int row0 = bm + wm + mt * 16 + quad * 4;
        u16x4 o;
#pragma unroll
        for (int r = 0; r < 4; ++r) o[r] = f2bf(acc[mt][nt][r] + bv);
        *(u16x4*)(a.Vt + (size_t)col * 4096 + row0) = o;
      }
    }
  } else if (z == 0) {
    // Q: prescaled by log2e, hi/lo split (lo kept for accurate logits)
#pragma unroll
    for (int mt = 0; mt < 4; ++mt)
#pragma unroll
      for (int nt = 0; nt < 4; ++nt) {
        int col = bn + wn + nt * 16 + l16;
        float bv = bias[col];
#pragma unroll
        for (int r = 0; r < 4; ++r) {
          int row = bm + wm + mt * 16 + quad * 4 + r;
          float v = (acc[mt][nt][r] + bv) * L2E;
          u16 h = f2bf(v);
          size_t oidx = (size_t)row * 512 + col;
          a.Qh[oidx] = h;
          a.Ql[oidx] = f2bf(v - bf2f(h));
        }
      }
  } else {
    // K: single bf16 (rounding noise ~ existing P-trunc error)
#pragma unroll
    for (int mt = 0; mt < 4; ++mt)
#pragma unroll
      for (int nt = 0; nt < 4; ++nt) {
        int col = bn + wn + nt * 16 + l16;
        float bv = bias[col];
#pragma unroll
        for (int r = 0; r < 4; ++r) {
          int row = bm + wm + mt * 16 + quad * 4 + r;
          a.Kh[(size_t)row * 512 + col] = f2bf(acc[mt][nt][r] + bv);
        }
      }
  }
}

// ---------------- generic staged GEMM: C[M,N] = A[M,K] @ B^T[N,K] + bias ----------------
template <int RELU, int BF16OUT>
__global__ __launch_bounds__(256) void gemm_bt(const u16* __restrict__ Ah,
                                               const u16* __restrict__ Bh,
                                               const float* __restrict__ bias,
                                               float* __restrict__ Cf,
                                               u16* __restrict__ Ch,
                                               int N, int K) {
  const int bn = blockIdx.x * 128, bm = blockIdx.y * 128;
  const int tid = threadIdx.x;
  const int wave = tid >> 6, lane = tid & 63;
  const int l16 = lane & 15, quad = lane >> 4;
  const int wm = (wave >> 1) * 64, wn = (wave & 1) * 64;

  __shared__ u16 sA[128 * 32];
  __shared__ u16 sB[128 * 32];

  const int srow = wave * 32 + (lane >> 2);
  const int scol = (lane & 3) * 8;
  const u16* srcA0 = Ah + (size_t)(bm + srow) * K + scol;
  const u16* srcB0 = Bh + (size_t)(bn + srow) * K + scol;
  const size_t half_off = (size_t)16 * K;
  u16* dstA = sA + wave * 1024;
  u16* dstB = sB + wave * 1024;

  f32x4 acc[4][4] = {};

  for (int kt = 0; kt < K; kt += 32) {
    gload_lds16(srcA0 + kt, dstA);
    gload_lds16(srcA0 + half_off + kt, dstA + 512);
    gload_lds16(srcB0 + kt, dstB);
    gload_lds16(srcB0 + half_off + kt, dstB + 512);
    __syncthreads();

    bf16x8 a_h[4], b_h[4];
#pragma unroll
    for (int mt = 0; mt < 4; ++mt)
      a_h[mt] = *(const bf16x8*)(sA + (wm + mt * 16 + l16) * 32 + quad * 8);
#pragma unroll
    for (int nt = 0; nt < 4; ++nt)
      b_h[nt] = *(const bf16x8*)(sB + (wn + nt * 16 + l16) * 32 + quad * 8);
#pragma unroll
    for (int mt = 0; mt < 4; ++mt)
#pragma unroll
      for (int nt = 0; nt < 4; ++nt)
        acc[mt][nt] = __builtin_amdgcn_mfma_f32_16x16x32_bf16(a_h[mt], b_h[nt], acc[mt][nt], 0, 0, 0);
    __syncthreads();
  }

#pragma unroll
  for (int mt = 0; mt < 4; ++mt)
#pragma unroll
    for (int nt = 0; nt < 4; ++nt) {
      int col = bn + wn + nt * 16 + l16;
      float bv = bias ? bias[col] : 0.f;
#pragma unroll
      for (int r = 0; r < 4; ++r) {
        int row = bm + wm + mt * 16 + quad * 4 + r;
        float v = acc[mt][nt][r] + bv;
        if (RELU) v = fmaxf(v, 0.f);
        size_t oidx = (size_t)row * N + col;
        if (BF16OUT) Ch[oidx] = f2bf(v);
        else Cf[oidx] = v;
      }
    }
}

// ---------------- flash attention v3: S^T form, 32q/wave, 64-key iters ----------------
// Grid (32 = 8h x 4chunk, 32 qb of 128 rows). Wave covers 32 q (2 m-tiles).
// S^T = K·Q (A=K dim-major from LDS, B=Q dim-major prefetched regs, Q hi/lo,
// K single bf16). P lands in C-layout with q = lane&15 -> 4-key-contiguous
// ds_write_b64 to LDS, verified A-layout read for PV. l computed via a
// constant-1.0 V row (5th n-tile). Q prescaled by log2e at QKV epilogue.
__global__ __launch_bounds__(256) void attn(const u16* __restrict__ Qh, const u16* __restrict__ Ql,
                                            const u16* __restrict__ Kh, const u16* __restrict__ Vt,
                                            const u64* __restrict__ mb64,
                                            float* __restrict__ O0, float* __restrict__ O1,
                                            float* __restrict__ O2, float* __restrict__ O3,
                                            float* __restrict__ lp) {
  const int S = 4096, D = 512;
  const int h = blockIdx.x >> 2, chunk = blockIdx.x & 3;
  const int tid = threadIdx.x, wave = tid >> 6, lane = tid & 63;
  const int l16 = lane & 15, quad = lane >> 4;
  const int q0w = blockIdx.y * 128 + wave * 32;
  const int kbeg = chunk * 1024;
  const int sw = l16 & 7;                       // bank-swizzle key

  __shared__ u16 sK[64 * 64];                   // [key][dim]   8 KB
  __shared__ u16 sV[80 * 64];                   // [dim][key]  10 KB (rows 64..79: ones/zeros)
  __shared__ u16 sP[4][32 * 64];                // per-wave P  16 KB
  u16* myP = &sP[wave][0];

  // ones row (dim 64 -> l column); zero rows 65..79
  if (tid < 16) ((u64*)(sV + 64 * 64))[tid] = 0x3F803F803F803F80ULL;
  for (int idx = tid; idx < 240; idx += 256) ((u64*)(sV + 65 * 64))[idx] = 0;

  // staging (swizzled on the global-source side; LDS dest is lane*16 contiguous)
  const int skey = lane >> 3;                   // 0..7 within wave's 8 rows
  const int sch  = lane & 7;
  const u16* srcK = Kh + (size_t)(kbeg + wave * 8 + skey) * D + h * 64 + ((sch ^ skey) * 8);
  const u16* srcV = Vt + (size_t)(h * 64 + wave * 8 + skey) * S + kbeg + ((sch ^ skey) * 8);
  u16* dstK = sK + wave * 512;
  u16* dstV = sV + wave * 512;

  // Q prefetch: B-frags (n=l16 -> q, k=quad*8 dims), hi + lo, 2 q-tiles x 2 dim-halves
  bf16x8 qfh[2][2], qfl[2][2];
#pragma unroll
  for (int qt = 0; qt < 2; ++qt)
#pragma unroll
    for (int kd = 0; kd < 2; ++kd) {
      size_t qb = (size_t)(q0w + qt * 16 + l16) * D + h * 64 + kd * 32 + quad * 8;
      qfh[qt][kd] = *(const bf16x8*)(Qh + qb);
      qfl[qt][kd] = *(const bf16x8*)(Ql + qb);
    }

  f32x4 accO[2][5] = {};
  const int wbase = kbeg >> 6;

  for (int it = 0; it < 16; ++it) {
    gload_lds16(srcK, dstK);
    gload_lds16(srcK + (size_t)32 * D, dstK + 32 * 64);
    gload_lds16(srcV, dstV);
    gload_lds16(srcV + (size_t)32 * S, dstV + 32 * 64);
    srcK += (size_t)64 * D; srcV += 64;
    __syncthreads();

    u64 wm[2];
#pragma unroll
    for (int qt = 0; qt < 2; ++qt)
      wm[qt] = mb64[(size_t)(q0w + qt * 16 + l16) * 64 + wbase + it];

#pragma unroll
    for (int half = 0; half < 2; ++half) {
      f32x4 sc[2][2];
#pragma unroll
      for (int k2 = 0; k2 < 2; ++k2) {
        const int kt4 = half * 2 + k2;
        const u16* arow = sK + (kt4 * 16 + l16) * 64;
        bf16x8 ka0 = *(const bf16x8*)(arow + ((quad ^ sw) * 8));
        bf16x8 ka1 = *(const bf16x8*)(arow + (((4 + quad) ^ sw) * 8));
#pragma unroll
        for (int qt = 0; qt < 2; ++qt) {
          f32x4 s = {};
          s = __builtin_amdgcn_mfma_f32_16x16x32_bf16(ka0, qfh[qt][0], s, 0, 0, 0);
          s = __builtin_amdgcn_mfma_f32_16x16x32_bf16(ka1, qfh[qt][1], s, 0, 0, 0);
          s = __builtin_amdgcn_mfma_f32_16x16x32_bf16(ka0, qfl[qt][0], s, 0, 0, 0);
          s = __builtin_amdgcn_mfma_f32_16x16x32_bf16(ka1, qfl[qt][1], s, 0, 0, 0);
          sc[k2][qt] = s;
        }
      }
#pragma unroll
      for (int k2 = 0; k2 < 2; ++k2) {
        const int kt4 = half * 2 + k2;
        const int baseb = (kt4 & 1) * 16 + quad * 4;
#pragma unroll
        for (int qt = 0; qt < 2; ++qt) {
          u32 wbits = half ? (u32)(wm[qt] >> 32) : (u32)wm[qt];
          float p[4];
#pragma unroll
          for (int r = 0; r < 4; ++r) {
            bool keep = (wbits >> (baseb + r)) & 1u;
            p[r] = exp2f(keep ? sc[k2][qt][r] : -1e9f);
          }
          int row = qt * 16 + l16;
          int pos = (kt4 * 2 + (quad >> 1)) ^ sw;
          u32x2 pk = {packtrunc(p[0], p[1]), packtrunc(p[2], p[3])};
          *(u32x2*)(myP + row * 64 + pos * 8 + (quad & 1) * 4) = pk;
        }
      }
    }
    // same-wave LDS RAW (myP wave-private): compiler lgkmcnt orders it
#pragma unroll
    for (int kt2 = 0; kt2 < 2; ++kt2) {
      bf16x8 pa[2];
#pragma unroll
      for (int qt = 0; qt < 2; ++qt)
        pa[qt] = *(const bf16x8*)(myP + (qt * 16 + l16) * 64 + (((kt2 * 4 + quad) ^ sw) * 8));
#pragma unroll
      for (int nt = 0; nt < 5; ++nt) {
        bf16x8 vf = *(const bf16x8*)(sV + (nt * 16 + l16) * 64 + (((kt2 * 4 + quad) ^ sw) * 8));
#pragma unroll
        for (int qt = 0; qt < 2; ++qt)
          accO[qt][nt] = __builtin_amdgcn_mfma_f32_16x16x32_bf16(pa[qt], vf, accO[qt][nt], 0, 0, 0);
      }
    }
    __syncthreads();
  }

  float* Op = (chunk < 2) ? (chunk ? O1 : O0) : (chunk == 2 ? O2 : O3);
#pragma unroll
  for (int qt = 0; qt < 2; ++qt)
#pragma unroll
    for (int nt = 0; nt < 4; ++nt)
#pragma unroll
      for (int r = 0; r < 4; ++r) {
        int row = q0w + qt * 16 + quad * 4 + r;
        Op[((size_t)h * S + row) * 64 + nt * 16 + l16] = accO[qt][nt][r];
      }
  if (l16 == 0)
#pragma unroll
    for (int qt = 0; qt < 2; ++qt)
#pragma unroll
      for (int r = 0; r < 4; ++r)
        lp[((size_t)h * 4 + chunk) * S + q0w + qt * 16 + quad * 4 + r] = accO[qt][4][r];
}

// ---------------- combine split-K partials -> ctx (bf16) ----------------
__global__ __launch_bounds__(256) void attn_combine(const float* __restrict__ O0,
                                                    const float* __restrict__ O1,
                                                    const float* __restrict__ O2,
                                                    const float* __restrict__ O3,
                                                    const float* __restrict__ lp,
                                                    u16* __restrict__ ctx) {
  const int S = 4096;
  int i = (blockIdx.x * 256 + threadIdx.x);
  int row = i >> 7;
  int col4 = (i & 127) * 4;
  int h = col4 >> 6, c = col4 & 63;
  size_t ob = ((size_t)h * S + row) * 64 + c;
  f32x4 o = *(const f32x4*)(O0 + ob) + *(const f32x4*)(O1 + ob) +
            *(const f32x4*)(O2 + ob) + *(const f32x4*)(O3 + ob);
  float l = lp[((size_t)h * 4 + 0) * S + row] + lp[((size_t)h * 4 + 1) * S + row] +
            lp[((size_t)h * 4 + 2) * S + row] + lp[((size_t)h * 4 + 3) * S + row];
  float rl = 1.f / l;
  u16x4 out;
#pragma unroll
  for (int j = 0; j < 4; ++j) out[j] = f2bf(o[j] * rl);
  *(u16x4*)(ctx + (size_t)row * 512 + col4) = out;
}

// ---------------- residual + layernorm (rows of 512) ----------------
__global__ __launch_bounds__(256) void resid_ln(const float* __restrict__ X,
                                                const float* __restrict__ Y,
                                                const float* __restrict__ g,
                                                const float* __restrict__ b,
                                                float* __restrict__ outF,
                                                u16* __restrict__ outH) {
  int row = blockIdx.x * 4 + (int)(threadIdx.x >> 6);
  int lane = threadIdx.x & 63;
  const float* x0 = X + (size_t)row * 512;
  const float* y0 = Y + (size_t)row * 512;
  int c0 = lane * 4, c1 = 256 + lane * 4;
  f32x4 v0 = *(const f32x4*)(x0 + c0) + *(const f32x4*)(y0 + c0);
  f32x4 v1 = *(const f32x4*)(x0 + c1) + *(const f32x4*)(y0 + c1);
  float s = 0.f, s2 = 0.f;
#pragma unroll
  for (int j = 0; j < 4; ++j) {
    s += v0[j] + v1[j];
    s2 += v0[j] * v0[j] + v1[j] * v1[j];
  }
#pragma unroll
  for (int m = 1; m < 64; m <<= 1) {
    s += __shfl_xor(s, m);
    s2 += __shfl_xor(s2, m);
  }
  float mean = s * (1.f / 512.f);
  float var = s2 * (1.f / 512.f) - mean * mean;
  float rs = rsqrtf(var + 1e-5f);
  f32x4 o0, o1;
#pragma unroll
  for (int j = 0; j < 4; ++j) {
    o0[j] = (v0[j] - mean) * rs * g[c0 + j] + b[c0 + j];
    o1[j] = (v1[j] - mean) * rs * g[c1 + j] + b[c1 + j];
  }
  if (outF) {
    *(f32x4*)(outF + (size_t)row * 512 + c0) = o0;
    *(f32x4*)(outF + (size_t)row * 512 + c1) = o1;
  }
  if (outH) {
    u16x4 h0, h1;
#pragma unroll
    for (int j = 0; j < 4; ++j) { h0[j] = f2bf(o0[j]); h1[j] = f2bf(o1[j]); }
    *(u16x4*)(outH + (size_t)row * 512 + c0) = h0;
    *(u16x4*)(outH + (size_t)row * 512 + c1) = h1;
  }
}

extern "C" void kernel_launch(void* const* d_in, const int* in_sizes, int n_in,
                              void* d_out, int out_size, void* d_ws, size_t ws_size,
                              hipStream_t stream) {
  (void)in_sizes; (void)n_in; (void)out_size; (void)ws_size;
  const float* x   = (const float*)d_in[0];
  const int*   mask= (const int*)d_in[1];
  const float* wq  = (const float*)d_in[2];
  const float* bq  = (const float*)d_in[3];
  const float* wk  = (const float*)d_in[4];
  const float* bk  = (const float*)d_in[5];
  const float* wv  = (const float*)d_in[6];
  const float* bv  = (const float*)d_in[7];
  const float* wo  = (const float*)d_in[8];
  const float* bo  = (const float*)d_in[9];
  const float* w1  = (const float*)d_in[10];
  const float* b1  = (const float*)d_in[11];
  const float* w2  = (const float*)d_in[12];
  const float* b2  = (const float*)d_in[13];
  const float* g1  = (const float*)d_in[14];
  const float* be1 = (const float*)d_in[15];
  const float* g2  = (const float*)d_in[16];
  const float* be2 = (const float*)d_in[17];

  const int S = 4096, D = 512, F = 2048;
  char* ws = (char*)d_ws;
  size_t cur = 0;
  auto alloc = [&](size_t bytes) {
    char* p = ws + cur;
    cur += (bytes + 255) & ~(size_t)255;
    return p;
  };
  u16* wqT_h = (u16*)alloc((size_t)D * D * 2); u16* wqT_l = (u16*)alloc((size_t)D * D * 2);
  u16* wkT_h = (u16*)alloc((size_t)D * D * 2); u16* wkT_l = (u16*)alloc((size_t)D * D * 2);
  u16* wvT_h = (u16*)alloc((size_t)D * D * 2); u16* wvT_l = (u16*)alloc((size_t)D * D * 2);
  u16* woT_h = (u16*)alloc((size_t)D * D * 2); u16* woT_l = (u16*)alloc((size_t)D * D * 2);
  u16* w1T_h = (u16*)alloc((size_t)D * F * 2); u16* w1T_l = (u16*)alloc((size_t)D * F * 2);
  u16* w2T_h = (u16*)alloc((size_t)D * F * 2); u16* w2T_l = (u16*)alloc((size_t)D * F * 2);
  u32* mbits = (u32*)alloc((size_t)S * S / 8);
  u16* xh = (u16*)alloc((size_t)S * D * 2);
  u16* xl = (u16*)alloc((size_t)S * D * 2);
  // Qh,Ql,Kh,Vt contiguous (16MB) so FF1's hbuf can alias the whole span
  u16* Qh = (u16*)alloc((size_t)S * D * 2);
  u16* Ql = (u16*)alloc((size_t)S * D * 2);
  u16* Kh = (u16*)alloc((size_t)S * D * 2);
  u16* Vt = (u16*)alloc((size_t)S * D * 2);
  u16* ctx = (u16*)alloc((size_t)S * D * 2);
  float* x1 = (float*)alloc((size_t)S * D * 4);
  u16* x1h = (u16*)alloc((size_t)S * D * 2);
  float* Oex = (float*)alloc((size_t)2 * S * D * 4);   // O2,O3 (16MB fresh)
  // aliases (lifetimes disjoint by stream order):
  float* O0 = (float*)xh;     // 8MB over xh+xl (dead after QKV gemm)
  float* O1 = x1;             // 8MB (x1 written later by resid_ln, after combine)
  float* O2 = Oex;
  float* O3 = Oex + (size_t)S * D;
  float* lp = (float*)x1h;    // 512KB (x1h written later by resid_ln)
  float* proj = (float*)xh;   // OP output, after combine read O0
  u16* hbuf = Qh;             // FF1 output (16MB over Qh..Vt), after attn
  float* ff2 = Oex;           // FF2 output, after combine read O2/O3

  PrepArgs pa;
  pa.x = x; pa.xh = xh; pa.xl = xl;
  pa.mask = mask; pa.mbits = (unsigned long long*)mbits;
  pa.pw[0] = {wq, wqT_h, wqT_l, D, D, 15, 4};
  pa.pw[1] = {wk, wkT_h, wkT_l, D, D, 15, 4};
  pa.pw[2] = {wv, wvT_h, wvT_l, D, D, 15, 4};
  pa.pw[3] = {wo, woT_h, woT_l, D, D, 15, 4};
  pa.pw[4] = {w1, w1T_h, w1T_l, D, F, 63, 6};
  pa.pw[5] = {w2, w2T_h, w2T_l, F, D, 15, 4};

  QkvArgs qa;
  qa.Ah = xh; qa.Al = xl;
  qa.Bh[0] = wqT_h; qa.Bh[1] = wkT_h; qa.Bh[2] = wvT_h;
  qa.Bl[0] = wqT_l; qa.Bl[1] = wkT_l; qa.Bl[2] = wvT_l;
  qa.bias[0] = bq; qa.bias[1] = bk; qa.bias[2] = bv;
  qa.Qh = Qh; qa.Ql = Ql; qa.Kh = Kh; qa.Vt = Vt;

  // 1. fused prep
  prep<<<70656, 256, 0, stream>>>(pa);
  // 2. QKV projection (Q prescaled hi/lo, K bf16, V transposed)
  gemm_qkv<<<dim3(4, 32, 3), 256, 0, stream>>>(qa);
  // 3. flash attention (S^T form, split-K x4) + combine
  attn<<<dim3(32, 32), 256, 0, stream>>>(Qh, Ql, Kh, Vt, (const u64*)mbits, O0, O1, O2, O3, lp);
  attn_combine<<<(S * D / 4) / 256, 256, 0, stream>>>(O0, O1, O2, O3, lp, ctx);
  // 4. output projection -> proj fp32
  gemm_bt<0, 0><<<dim3(4, 32), 256, 0, stream>>>(ctx, woT_h, bo, proj, nullptr, D, D);
  // 5. residual + LN1
  resid_ln<<<S / 4, 256, 0, stream>>>(x, proj, g1, be1, x1, x1h);
  // 6. FFN
  gemm_bt<1, 1><<<dim3(16, 32), 256, 0, stream>>>(x1h, w1T_h, b1, nullptr, hbuf, F, D);
  gemm_bt<0, 0><<<dim3(4, 32), 256, 0, stream>>>(hbuf, w2T_h, b2, ff2, nullptr, D, F);
  // 7. residual + LN2 -> final fp32 output
  resid_ln<<<S / 4, 256, 0, stream>>>(x1, ff2, g2, be2, (float*)d_out, nullptr);
}

// Round 7
// 355.209 us; speedup vs baseline: 2.2831x; 1.0438x over previous
//
#include <hip/hip_runtime.h>

typedef unsigned short u16;
typedef unsigned int u32;
typedef unsigned long long u64;
typedef __attribute__((ext_vector_type(4))) float f32x4;
typedef __attribute__((ext_vector_type(8))) short bf16x8;   // 8 bf16 (4 VGPRs)
typedef __attribute__((ext_vector_type(4))) u16 u16x4;
typedef __attribute__((ext_vector_type(2))) u32 u32x2;

#define DEV __device__ __forceinline__

DEV u16 f2bf(float f) {               // RNE fp32 -> bf16
  union { float f; u32 u; } c; c.f = f;
  u32 u = c.u;
  u += 0x7fffu + ((u >> 16) & 1u);
  return (u16)(u >> 16);
}
DEV float bf2f(u16 h) {
  union { u32 u; float f; } c; c.u = ((u32)h) << 16;
  return c.f;
}
DEV u32 fbits(float f) { union { float f; u32 u; } c; c.f = f; return c.u; }
// pack two fp32 -> two truncated bf16 in one u32 (a = low, b = high)
DEV u32 packtrunc(float a, float b) {
  return (fbits(b) & 0xFFFF0000u) | (fbits(a) >> 16);
}

// async global->LDS, 16B per lane. Dest is WAVE-UNIFORM base + lane*16 (m104/m108).
DEV void gload_lds16(const void* g, void* l) {
  __builtin_amdgcn_global_load_lds(
      (const __attribute__((address_space(1))) u32*)(u64)g,
      (__attribute__((address_space(3))) u32*)(u32)(u64)l,   // low 32 bits = LDS offset
      16, 0, 0);
}

// ---------------- fused prep: x split + 6 weight transposes + mask pack ----------------
struct PrepW { const float* w; u16* th; u16* tl; int R, C, gxmask, gxshift; };
struct PrepArgs {
  const float* x; u16* xh; u16* xl;
  const int* mask; unsigned long long* mbits;
  PrepW pw[6];
};

__global__ __launch_bounds__(256) void prep(PrepArgs a) {
  __shared__ float t[32][33];
  int b = blockIdx.x, tid = threadIdx.x;
  if (b < 2048) {                       // x -> bf16 hi/lo
    int i = (b * 256 + tid) * 4;
    f32x4 v = *(const f32x4*)(a.x + i);
    u16x4 h, l;
#pragma unroll
    for (int j = 0; j < 4; ++j) { h[j] = f2bf(v[j]); l[j] = f2bf(v[j] - bf2f(h[j])); }
    *(u16x4*)(a.xh + i) = h;
    *(u16x4*)(a.xl + i) = l;
    return;
  }
  b -= 2048;
  if (b < 3072) {                       // weight (R,C) -> transposed hi/lo (C,R)
    int wi, base;
    if (b < 1024) { wi = b >> 8; base = b & 255; }
    else if (b < 2048) { wi = 4; base = b - 1024; }
    else { wi = 5; base = b - 2048; }
    PrepW p = a.pw[wi];
    int c0 = (base & p.gxmask) * 32, r0 = (base >> p.gxshift) * 32;
    int tx = tid & 31, ty = tid >> 5;
#pragma unroll
    for (int i = 0; i < 4; ++i)
      t[ty + 8 * i][tx] = p.w[(size_t)(r0 + ty + 8 * i) * p.C + c0 + tx];
    __syncthreads();
#pragma unroll
    for (int i = 0; i < 4; ++i) {
      float v = t[tx][ty + 8 * i];
      u16 h = f2bf(v);
      size_t o = (size_t)(c0 + ty + 8 * i) * p.R + r0 + tx;
      p.th[o] = h;
      p.tl[o] = f2bf(v - bf2f(h));
    }
    return;
  }
  b -= 3072;                            // mask -> bitmask
  size_t i = (size_t)b * 256 + tid;
  unsigned long long bb = __ballot(a.mask[i] != 0);
  if ((tid & 63) == 0) a.mbits[i >> 6] = bb;
}

// ---------------- QKV GEMM: staged, hi/lo split (3 MFMA) ----------------
// z=0 -> Qh/Ql (prescaled by log2e), z=1 -> Kh, z=2 -> Vt (transposed bf16).
struct QkvArgs {
  const u16 *Ah, *Al;
  const u16 *Bh[3], *Bl[3];
  const float* bias[3];
  u16 *Qh, *Ql, *Kh, *Vt;
};

__global__ __launch_bounds__(256) void gemm_qkv(QkvArgs a) {
  const int K = 512;
  const float L2E = 1.44269504088896340736f;
  const int z = blockIdx.z;
  const u16* __restrict__ Bh = a.Bh[z];
  const u16* __restrict__ Bl = a.Bl[z];
  const float* __restrict__ bias = a.bias[z];
  const int bn = blockIdx.x * 128, bm = blockIdx.y * 128;
  const int tid = threadIdx.x;
  const int wave = tid >> 6, lane = tid & 63;
  const int l16 = lane & 15, quad = lane >> 4;
  const int wm = (wave >> 1) * 64, wn = (wave & 1) * 64;

  __shared__ u16 sA[128 * 32];
  __shared__ u16 sB[128 * 32];
  __shared__ u16 sAl[128 * 32];
  __shared__ u16 sBl[128 * 32];

  const int srow = wave * 32 + (lane >> 2);
  const int scol = (lane & 3) * 8;
  const u16* srcA0 = a.Ah + (size_t)(bm + srow) * K + scol;
  const u16* srcB0 = Bh + (size_t)(bn + srow) * K + scol;
  const u16* srcAl0 = a.Al + (size_t)(bm + srow) * K + scol;
  const u16* srcBl0 = Bl + (size_t)(bn + srow) * K + scol;
  const size_t half_off = (size_t)16 * K;
  u16* dstA = sA + wave * 1024;
  u16* dstB = sB + wave * 1024;
  u16* dstAl = sAl + wave * 1024;
  u16* dstBl = sBl + wave * 1024;

  f32x4 acc[4][4] = {};

  for (int kt = 0; kt < K; kt += 32) {
    gload_lds16(srcA0 + kt, dstA);
    gload_lds16(srcA0 + half_off + kt, dstA + 512);
    gload_lds16(srcB0 + kt, dstB);
    gload_lds16(srcB0 + half_off + kt, dstB + 512);
    gload_lds16(srcAl0 + kt, dstAl);
    gload_lds16(srcAl0 + half_off + kt, dstAl + 512);
    gload_lds16(srcBl0 + kt, dstBl);
    gload_lds16(srcBl0 + half_off + kt, dstBl + 512);
    __syncthreads();

    bf16x8 a_h[4], b_h[4], a_l[4], b_l[4];
#pragma unroll
    for (int mt = 0; mt < 4; ++mt) {
      a_h[mt] = *(const bf16x8*)(sA + (wm + mt * 16 + l16) * 32 + quad * 8);
      a_l[mt] = *(const bf16x8*)(sAl + (wm + mt * 16 + l16) * 32 + quad * 8);
    }
#pragma unroll
    for (int nt = 0; nt < 4; ++nt) {
      b_h[nt] = *(const bf16x8*)(sB + (wn + nt * 16 + l16) * 32 + quad * 8);
      b_l[nt] = *(const bf16x8*)(sBl + (wn + nt * 16 + l16) * 32 + quad * 8);
    }
#pragma unroll
    for (int mt = 0; mt < 4; ++mt)
#pragma unroll
      for (int nt = 0; nt < 4; ++nt) {
        acc[mt][nt] = __builtin_amdgcn_mfma_f32_16x16x32_bf16(a_h[mt], b_h[nt], acc[mt][nt], 0, 0, 0);
        acc[mt][nt] = __builtin_amdgcn_mfma_f32_16x16x32_bf16(a_h[mt], b_l[nt], acc[mt][nt], 0, 0, 0);
        acc[mt][nt] = __builtin_amdgcn_mfma_f32_16x16x32_bf16(a_l[mt], b_h[nt], acc[mt][nt], 0, 0, 0);
      }
    __syncthreads();
  }

  if (z == 2) {
    // V: write transposed bf16 Vt[dim][seq]; r-regs are seq-contiguous -> 8B stores
#pragma unroll
    for (int nt = 0; nt < 4; ++nt) {
      int col = bn + wn + nt * 16 + l16;
      float bv = bias[col];
#pragma unroll
      for (int mt = 0; mt < 4; ++mt) {
        int row0 = bm + wm + mt * 16 + quad * 4;
        u16x4 o;
#pragma unroll
        for (int r = 0; r < 4; ++r) o[r] = f2bf(acc[mt][nt][r] + bv);
        *(u16x4*)(a.Vt + (size_t)col * 4096 + row0) = o;
      }
    }
  } else if (z == 0) {
    // Q: prescaled by log2e, hi/lo split (lo kept for accurate logits)
#pragma unroll
    for (int mt = 0; mt < 4; ++mt)
#pragma unroll
      for (int nt = 0; nt < 4; ++nt) {
        int col = bn + wn + nt * 16 + l16;
        float bv = bias[col];
#pragma unroll
        for (int r = 0; r < 4; ++r) {
          int row = bm + wm + mt * 16 + quad * 4 + r;
          float v = (acc[mt][nt][r] + bv) * L2E;
          u16 h = f2bf(v);
          size_t oidx = (size_t)row * 512 + col;
          a.Qh[oidx] = h;
          a.Ql[oidx] = f2bf(v - bf2f(h));
        }
      }
  } else {
    // K: single bf16 (rounding noise ~ existing P-trunc error)
#pragma unroll
    for (int mt = 0; mt < 4; ++mt)
#pragma unroll
      for (int nt = 0; nt < 4; ++nt) {
        int col = bn + wn + nt * 16 + l16;
        float bv = bias[col];
#pragma unroll
        for (int r = 0; r < 4; ++r) {
          int row = bm + wm + mt * 16 + quad * 4 + r;
          a.Kh[(size_t)row * 512 + col] = f2bf(acc[mt][nt][r] + bv);
        }
      }
  }
}

// ---------------- generic staged GEMM, DOUBLE-BUFFERED (1 barrier / K-step) ----------
// Prefetch for step i+1 issued right AFTER the barrier, so the next barrier's
// vmcnt(0) drain finds the loads already complete (kills the m97 stall).
template <int RELU, int BF16OUT>
__global__ __launch_bounds__(256) void gemm_bt(const u16* __restrict__ Ah,
                                               const u16* __restrict__ Bh,
                                               const float* __restrict__ bias,
                                               float* __restrict__ Cf,
                                               u16* __restrict__ Ch,
                                               int N, int K) {
  const int bn = blockIdx.x * 128, bm = blockIdx.y * 128;
  const int tid = threadIdx.x;
  const int wave = tid >> 6, lane = tid & 63;
  const int l16 = lane & 15, quad = lane >> 4;
  const int wm = (wave >> 1) * 64, wn = (wave & 1) * 64;

  __shared__ u16 sA[2][128 * 32];
  __shared__ u16 sB[2][128 * 32];

  const int srow = wave * 32 + (lane >> 2);
  const int scol = (lane & 3) * 8;
  const u16* srcA0 = Ah + (size_t)(bm + srow) * K + scol;
  const u16* srcB0 = Bh + (size_t)(bn + srow) * K + scol;
  const size_t half_off = (size_t)16 * K;

  auto prefetchG = [&](int kt, int buf) {
    u16* dA = sA[buf] + wave * 1024;
    u16* dB = sB[buf] + wave * 1024;
    gload_lds16(srcA0 + kt, dA);
    gload_lds16(srcA0 + half_off + kt, dA + 512);
    gload_lds16(srcB0 + kt, dB);
    gload_lds16(srcB0 + half_off + kt, dB + 512);
  };

  f32x4 acc[4][4] = {};
  prefetchG(0, 0);

  const int steps = K >> 5;
  for (int i = 0; i < steps; ++i) {
    __syncthreads();                       // drains prefetch issued one compute-phase ago
    if (i + 1 < steps) prefetchG((i + 1) << 5, (i + 1) & 1);
    const u16* bufA = sA[i & 1];
    const u16* bufB = sB[i & 1];

    bf16x8 a_h[4], b_h[4];
#pragma unroll
    for (int mt = 0; mt < 4; ++mt)
      a_h[mt] = *(const bf16x8*)(bufA + (wm + mt * 16 + l16) * 32 + quad * 8);
#pragma unroll
    for (int nt = 0; nt < 4; ++nt)
      b_h[nt] = *(const bf16x8*)(bufB + (wn + nt * 16 + l16) * 32 + quad * 8);
#pragma unroll
    for (int mt = 0; mt < 4; ++mt)
#pragma unroll
      for (int nt = 0; nt < 4; ++nt)
        acc[mt][nt] = __builtin_amdgcn_mfma_f32_16x16x32_bf16(a_h[mt], b_h[nt], acc[mt][nt], 0, 0, 0);
  }

#pragma unroll
  for (int mt = 0; mt < 4; ++mt)
#pragma unroll
    for (int nt = 0; nt < 4; ++nt) {
      int col = bn + wn + nt * 16 + l16;
      float bv = bias ? bias[col] : 0.f;
#pragma unroll
      for (int r = 0; r < 4; ++r) {
        int row = bm + wm + mt * 16 + quad * 4 + r;
        float v = acc[mt][nt][r] + bv;
        if (RELU) v = fmaxf(v, 0.f);
        size_t oidx = (size_t)row * N + col;
        if (BF16OUT) Ch[oidx] = f2bf(v);
        else Cf[oidx] = v;
      }
    }
}

// ---------------- flash attention v4: S^T form + double-buffered K/V ----------------
// Grid (32 = 8h x 4chunk, 32 qb of 128 rows). Wave covers 32 q (2 m-tiles).
// ONE barrier per 64-key iter; K/V prefetch for iter i+1 issued right after the
// barrier (loads complete during iter i's compute -> cheap drain). Mask words
// prefetched one iter ahead into registers. l via constant-1.0 V row.
__global__ __launch_bounds__(256) void attn(const u16* __restrict__ Qh, const u16* __restrict__ Ql,
                                            const u16* __restrict__ Kh, const u16* __restrict__ Vt,
                                            const u64* __restrict__ mb64,
                                            float* __restrict__ O0, float* __restrict__ O1,
                                            float* __restrict__ O2, float* __restrict__ O3,
                                            float* __restrict__ lp) {
  const int S = 4096, D = 512;
  const int h = blockIdx.x >> 2, chunk = blockIdx.x & 3;
  const int tid = threadIdx.x, wave = tid >> 6, lane = tid & 63;
  const int l16 = lane & 15, quad = lane >> 4;
  const int q0w = blockIdx.y * 128 + wave * 32;
  const int kbeg = chunk * 1024;
  const int sw = l16 & 7;                       // bank-swizzle key

  __shared__ u16 sK[2][64 * 64];                // [key][dim]  2 x 8 KB
  __shared__ u16 sV[2][80 * 64];                // [dim][key]  2 x 10 KB (row 64: ones)
  __shared__ u16 sP[4][32 * 64];                // per-wave P  16 KB
  u16* myP = &sP[wave][0];

  // ones row (dim 64 -> l column) in BOTH buffers; rows 65..79 garbage (outputs unused)
  if (tid < 16) {
    ((u64*)(sV[0] + 64 * 64))[tid] = 0x3F803F803F803F80ULL;
    ((u64*)(sV[1] + 64 * 64))[tid] = 0x3F803F803F803F80ULL;
  }

  // staging (swizzled on the global-source side; LDS dest is lane*16 contiguous)
  const int skey = lane >> 3;                   // 0..7
  const int sch  = lane & 7;
  const u16* srcK = Kh + (size_t)(kbeg + wave * 8 + skey) * D + h * 64 + ((sch ^ skey) * 8);
  const u16* srcV = Vt + (size_t)(h * 64 + wave * 8 + skey) * S + kbeg + ((sch ^ skey) * 8);

  auto prefetchKV = [&](int it) {
    int buf = it & 1;
    const u16* pK = srcK + (size_t)it * 64 * D;
    const u16* pV = srcV + it * 64;
    u16* dK = sK[buf] + wave * 512;
    u16* dV = sV[buf] + wave * 512;
    gload_lds16(pK, dK);
    gload_lds16(pK + (size_t)32 * D, dK + 32 * 64);
    gload_lds16(pV, dV);
    gload_lds16(pV + (size_t)32 * S, dV + 32 * 64);
  };

  // Q prefetch: B-frags (n=l16 -> q, k=quad*8 dims), hi + lo
  bf16x8 qfh[2][2], qfl[2][2];
#pragma unroll
  for (int qt = 0; qt < 2; ++qt)
#pragma unroll
    for (int kd = 0; kd < 2; ++kd) {
      size_t qb = (size_t)(q0w + qt * 16 + l16) * D + h * 64 + kd * 32 + quad * 8;
      qfh[qt][kd] = *(const bf16x8*)(Qh + qb);
      qfl[qt][kd] = *(const bf16x8*)(Ql + qb);
    }

  f32x4 accO[2][5] = {};
  const int wbase = kbeg >> 6;

  prefetchKV(0);
  u64 wmCur[2];
#pragma unroll
  for (int qt = 0; qt < 2; ++qt)
    wmCur[qt] = mb64[(size_t)(q0w + qt * 16 + l16) * 64 + wbase];

  for (int it = 0; it < 16; ++it) {
    __syncthreads();                     // drains prefetch issued one compute-phase ago
    if (it + 1 < 16) prefetchKV(it + 1);
    u64 wmNext[2] = {0, 0};
    if (it + 1 < 16) {
#pragma unroll
      for (int qt = 0; qt < 2; ++qt)
        wmNext[qt] = mb64[(size_t)(q0w + qt * 16 + l16) * 64 + wbase + it + 1];
    }
    const u16* bK = sK[it & 1];
    const u16* bV = sV[it & 1];

#pragma unroll
    for (int half = 0; half < 2; ++half) {
      f32x4 sc[2][2];
#pragma unroll
      for (int k2 = 0; k2 < 2; ++k2) {
        const int kt4 = half * 2 + k2;
        const u16* arow = bK + (kt4 * 16 + l16) * 64;
        bf16x8 ka0 = *(const bf16x8*)(arow + ((quad ^ sw) * 8));
        bf16x8 ka1 = *(const bf16x8*)(arow + (((4 + quad) ^ sw) * 8));
#pragma unroll
        for (int qt = 0; qt < 2; ++qt) {
          f32x4 s = {};
          s = __builtin_amdgcn_mfma_f32_16x16x32_bf16(ka0, qfh[qt][0], s, 0, 0, 0);
          s = __builtin_amdgcn_mfma_f32_16x16x32_bf16(ka1, qfh[qt][1], s, 0, 0, 0);
          s = __builtin_amdgcn_mfma_f32_16x16x32_bf16(ka0, qfl[qt][0], s, 0, 0, 0);
          s = __builtin_amdgcn_mfma_f32_16x16x32_bf16(ka1, qfl[qt][1], s, 0, 0, 0);
          sc[k2][qt] = s;
        }
      }
#pragma unroll
      for (int k2 = 0; k2 < 2; ++k2) {
        const int kt4 = half * 2 + k2;
        const int baseb = (kt4 & 1) * 16 + quad * 4;
#pragma unroll
        for (int qt = 0; qt < 2; ++qt) {
          u32 wbits = half ? (u32)(wmCur[qt] >> 32) : (u32)wmCur[qt];
          float p[4];
#pragma unroll
          for (int r = 0; r < 4; ++r) {
            bool keep = (wbits >> (baseb + r)) & 1u;
            p[r] = exp2f(keep ? sc[k2][qt][r] : -1e9f);
          }
          int row = qt * 16 + l16;
          int pos = (kt4 * 2 + (quad >> 1)) ^ sw;
          u32x2 pk = {packtrunc(p[0], p[1]), packtrunc(p[2], p[3])};
          *(u32x2*)(myP + row * 64 + pos * 8 + (quad & 1) * 4) = pk;
        }
      }
    }
    // same-wave LDS RAW (myP wave-private): compiler lgkmcnt orders it
#pragma unroll
    for (int kt2 = 0; kt2 < 2; ++kt2) {
      bf16x8 pa[2];
#pragma unroll
      for (int qt = 0; qt < 2; ++qt)
        pa[qt] = *(const bf16x8*)(myP + (qt * 16 + l16) * 64 + (((kt2 * 4 + quad) ^ sw) * 8));
#pragma unroll
      for (int nt = 0; nt < 5; ++nt) {
        bf16x8 vf = *(const bf16x8*)(bV + (nt * 16 + l16) * 64 + (((kt2 * 4 + quad) ^ sw) * 8));
#pragma unroll
        for (int qt = 0; qt < 2; ++qt)
          accO[qt][nt] = __builtin_amdgcn_mfma_f32_16x16x32_bf16(pa[qt], vf, accO[qt][nt], 0, 0, 0);
      }
    }
    wmCur[0] = wmNext[0];
    wmCur[1] = wmNext[1];
  }

  float* Op = (chunk < 2) ? (chunk ? O1 : O0) : (chunk == 2 ? O2 : O3);
#pragma unroll
  for (int qt = 0; qt < 2; ++qt)
#pragma unroll
    for (int nt = 0; nt < 4; ++nt)
#pragma unroll
      for (int r = 0; r < 4; ++r) {
        int row = q0w + qt * 16 + quad * 4 + r;
        Op[((size_t)h * S + row) * 64 + nt * 16 + l16] = accO[qt][nt][r];
      }
  if (l16 == 0)
#pragma unroll
    for (int qt = 0; qt < 2; ++qt)
#pragma unroll
      for (int r = 0; r < 4; ++r)
        lp[((size_t)h * 4 + chunk) * S + q0w + qt * 16 + quad * 4 + r] = accO[qt][4][r];
}

// ---------------- combine split-K partials -> ctx (bf16) ----------------
__global__ __launch_bounds__(256) void attn_combine(const float* __restrict__ O0,
                                                    const float* __restrict__ O1,
                                                    const float* __restrict__ O2,
                                                    const float* __restrict__ O3,
                                                    const float* __restrict__ lp,
                                                    u16* __restrict__ ctx) {
  const int S = 4096;
  int i = (blockIdx.x * 256 + threadIdx.x);
  int row = i >> 7;
  int col4 = (i & 127) * 4;
  int h = col4 >> 6, c = col4 & 63;
  size_t ob = ((size_t)h * S + row) * 64 + c;
  f32x4 o = *(const f32x4*)(O0 + ob) + *(const f32x4*)(O1 + ob) +
            *(const f32x4*)(O2 + ob) + *(const f32x4*)(O3 + ob);
  float l = lp[((size_t)h * 4 + 0) * S + row] + lp[((size_t)h * 4 + 1) * S + row] +
            lp[((size_t)h * 4 + 2) * S + row] + lp[((size_t)h * 4 + 3) * S + row];
  float rl = 1.f / l;
  u16x4 out;
#pragma unroll
  for (int j = 0; j < 4; ++j) out[j] = f2bf(o[j] * rl);
  *(u16x4*)(ctx + (size_t)row * 512 + col4) = out;
}

// ---------------- residual + layernorm (rows of 512) ----------------
__global__ __launch_bounds__(256) void resid_ln(const float* __restrict__ X,
                                                const float* __restrict__ Y,
                                                const float* __restrict__ g,
                                                const float* __restrict__ b,
                                                float* __restrict__ outF,
                                                u16* __restrict__ outH) {
  int row = blockIdx.x * 4 + (int)(threadIdx.x >> 6);
  int lane = threadIdx.x & 63;
  const float* x0 = X + (size_t)row * 512;
  const float* y0 = Y + (size_t)row * 512;
  int c0 = lane * 4, c1 = 256 + lane * 4;
  f32x4 v0 = *(const f32x4*)(x0 + c0) + *(const f32x4*)(y0 + c0);
  f32x4 v1 = *(const f32x4*)(x0 + c1) + *(const f32x4*)(y0 + c1);
  float s = 0.f, s2 = 0.f;
#pragma unroll
  for (int j = 0; j < 4; ++j) {
    s += v0[j] + v1[j];
    s2 += v0[j] * v0[j] + v1[j] * v1[j];
  }
#pragma unroll
  for (int m = 1; m < 64; m <<= 1) {
    s += __shfl_xor(s, m);
    s2 += __shfl_xor(s2, m);
  }
  float mean = s * (1.f / 512.f);
  float var = s2 * (1.f / 512.f) - mean * mean;
  float rs = rsqrtf(var + 1e-5f);
  f32x4 o0, o1;
#pragma unroll
  for (int j = 0; j < 4; ++j) {
    o0[j] = (v0[j] - mean) * rs * g[c0 + j] + b[c0 + j];
    o1[j] = (v1[j] - mean) * rs * g[c1 + j] + b[c1 + j];
  }
  if (outF) {
    *(f32x4*)(outF + (size_t)row * 512 + c0) = o0;
    *(f32x4*)(outF + (size_t)row * 512 + c1) = o1;
  }
  if (outH) {
    u16x4 h0, h1;
#pragma unroll
    for (int j = 0; j < 4; ++j) { h0[j] = f2bf(o0[j]); h1[j] = f2bf(o1[j]); }
    *(u16x4*)(outH + (size_t)row * 512 + c0) = h0;
    *(u16x4*)(outH + (size_t)row * 512 + c1) = h1;
  }
}

extern "C" void kernel_launch(void* const* d_in, const int* in_sizes, int n_in,
                              void* d_out, int out_size, void* d_ws, size_t ws_size,
                              hipStream_t stream) {
  (void)in_sizes; (void)n_in; (void)out_size; (void)ws_size;
  const float* x   = (const float*)d_in[0];
  const int*   mask= (const int*)d_in[1];
  const float* wq  = (const float*)d_in[2];
  const float* bq  = (const float*)d_in[3];
  const float* wk  = (const float*)d_in[4];
  const float* bk  = (const float*)d_in[5];
  const float* wv  = (const float*)d_in[6];
  const float* bv  = (const float*)d_in[7];
  const float* wo  = (const float*)d_in[8];
  const float* bo  = (const float*)d_in[9];
  const float* w1  = (const float*)d_in[10];
  const float* b1  = (const float*)d_in[11];
  const float* w2  = (const float*)d_in[12];
  const float* b2  = (const float*)d_in[13];
  const float* g1  = (const float*)d_in[14];
  const float* be1 = (const float*)d_in[15];
  const float* g2  = (const float*)d_in[16];
  const float* be2 = (const float*)d_in[17];

  const int S = 4096, D = 512, F = 2048;
  char* ws = (char*)d_ws;
  size_t cur = 0;
  auto alloc = [&](size_t bytes) {
    char* p = ws + cur;
    cur += (bytes + 255) & ~(size_t)255;
    return p;
  };
  u16* wqT_h = (u16*)alloc((size_t)D * D * 2); u16* wqT_l = (u16*)alloc((size_t)D * D * 2);
  u16* wkT_h = (u16*)alloc((size_t)D * D * 2); u16* wkT_l = (u16*)alloc((size_t)D * D * 2);
  u16* wvT_h = (u16*)alloc((size_t)D * D * 2); u16* wvT_l = (u16*)alloc((size_t)D * D * 2);
  u16* woT_h = (u16*)alloc((size_t)D * D * 2); u16* woT_l = (u16*)alloc((size_t)D * D * 2);
  u16* w1T_h = (u16*)alloc((size_t)D * F * 2); u16* w1T_l = (u16*)alloc((size_t)D * F * 2);
  u16* w2T_h = (u16*)alloc((size_t)D * F * 2); u16* w2T_l = (u16*)alloc((size_t)D * F * 2);
  u32* mbits = (u32*)alloc((size_t)S * S / 8);
  u16* xh = (u16*)alloc((size_t)S * D * 2);
  u16* xl = (u16*)alloc((size_t)S * D * 2);
  // Qh,Ql,Kh,Vt contiguous (16MB) so FF1's hbuf can alias the whole span
  u16* Qh = (u16*)alloc((size_t)S * D * 2);
  u16* Ql = (u16*)alloc((size_t)S * D * 2);
  u16* Kh = (u16*)alloc((size_t)S * D * 2);
  u16* Vt = (u16*)alloc((size_t)S * D * 2);
  u16* ctx = (u16*)alloc((size_t)S * D * 2);
  float* x1 = (float*)alloc((size_t)S * D * 4);
  u16* x1h = (u16*)alloc((size_t)S * D * 2);
  float* Oex = (float*)alloc((size_t)2 * S * D * 4);   // O2,O3 (16MB fresh)
  // aliases (lifetimes disjoint by stream order):
  float* O0 = (float*)xh;     // 8MB over xh+xl (dead after QKV gemm)
  float* O1 = x1;             // 8MB (x1 written later by resid_ln, after combine)
  float* O2 = Oex;
  float* O3 = Oex + (size_t)S * D;
  float* lp = (float*)x1h;    // 512KB (x1h written later by resid_ln)
  float* proj = (float*)xh;   // OP output, after combine read O0
  u16* hbuf = Qh;             // FF1 output (16MB over Qh..Vt), after attn
  float* ff2 = Oex;           // FF2 output, after combine read O2/O3

  PrepArgs pa;
  pa.x = x; pa.xh = xh; pa.xl = xl;
  pa.mask = mask; pa.mbits = (unsigned long long*)mbits;
  pa.pw[0] = {wq, wqT_h, wqT_l, D, D, 15, 4};
  pa.pw[1] = {wk, wkT_h, wkT_l, D, D, 15, 4};
  pa.pw[2] = {wv, wvT_h, wvT_l, D, D, 15, 4};
  pa.pw[3] = {wo, woT_h, woT_l, D, D, 15, 4};
  pa.pw[4] = {w1, w1T_h, w1T_l, D, F, 63, 6};
  pa.pw[5] = {w2, w2T_h, w2T_l, F, D, 15, 4};

  QkvArgs qa;
  qa.Ah = xh; qa.Al = xl;
  qa.Bh[0] = wqT_h; qa.Bh[1] = wkT_h; qa.Bh[2] = wvT_h;
  qa.Bl[0] = wqT_l; qa.Bl[1] = wkT_l; qa.Bl[2] = wvT_l;
  qa.bias[0] = bq; qa.bias[1] = bk; qa.bias[2] = bv;
  qa.Qh = Qh; qa.Ql = Ql; qa.Kh = Kh; qa.Vt = Vt;

  // 1. fused prep
  prep<<<70656, 256, 0, stream>>>(pa);
  // 2. QKV projection (Q prescaled hi/lo, K bf16, V transposed)
  gemm_qkv<<<dim3(4, 32, 3), 256, 0, stream>>>(qa);
  // 3. flash attention (S^T form, split-K x4, double-buffered) + combine
  attn<<<dim3(32, 32), 256, 0, stream>>>(Qh, Ql, Kh, Vt, (const u64*)mbits, O0, O1, O2, O3, lp);
  attn_combine<<<(S * D / 4) / 256, 256, 0, stream>>>(O0, O1, O2, O3, lp, ctx);
  // 4. output projection -> proj fp32
  gemm_bt<0, 0><<<dim3(4, 32), 256, 0, stream>>>(ctx, woT_h, bo, proj, nullptr, D, D);
  // 5. residual + LN1
  resid_ln<<<S / 4, 256, 0, stream>>>(x, proj, g1, be1, x1, x1h);
  // 6. FFN
  gemm_bt<1, 1><<<dim3(16, 32), 256, 0, stream>>>(x1h, w1T_h, b1, nullptr, hbuf, F, D);
  gemm_bt<0, 0><<<dim3(4, 32), 256, 0, stream>>>(hbuf, w2T_h, b2, ff2, nullptr, D, F);
  // 7. residual + LN2 -> final fp32 output
  resid_ln<<<S / 4, 256, 0, stream>>>(x1, ff2, g2, be2, (float*)d_out, nullptr);
}